// Round 2
// baseline (4262.848 us; speedup 1.0000x reference)
//
// Hyperbolic (Poincare ball) transformer block — MI355X round 2.
// fp32 correctness-first; round-1 crash diagnosed as d_ws overflow (needed
// 336 MB, never checked ws_size). This round: peak ws = 3*N*E + CH*E + norms
// = ~208.5 MB via chunked stage1/QKV (h1 lives only as a 16 MB chunk),
// in-place attention over Q, and buffer overlays (mo->K, h2->V, ffn-hidden->Q,
// m2->chunk buf). Guard: if ws_size still insufficient, launch nothing so the
// harness reports a clean absmax failure instead of a device fault.
#include <hip/hip_runtime.h>
#include <math.h>

#define S_DIM 128
#define B_DIM 256
#define E_DIM 512
#define F_DIM 2048
#define N_ROWS (S_DIM * B_DIM) /* 32768 */
#define CH 8192                /* row chunk */
#define MAXN 0.99999f          /* 1 - 1e-5 */

// ---------------- block-wide sum over 256 threads (4 waves) ----------------
__device__ __forceinline__ float blockSum256(float v, float* tmp) {
#pragma unroll
  for (int o = 32; o > 0; o >>= 1) v += __shfl_down(v, o);
  int lane = threadIdx.x & 63, wid = threadIdx.x >> 6;
  if (lane == 0) tmp[wid] = v;
  __syncthreads();
  if (threadIdx.x == 0) tmp[0] = tmp[0] + tmp[1] + tmp[2] + tmp[3];
  __syncthreads();
  float r = tmp[0];
  __syncthreads();
  return r;
}

// ---- stage 1: h1 = expmap0(LN(logmap0(x))), save |h1| (= tanh(|ln|)) ----
__global__ __launch_bounds__(256) void k_stage1(const float* __restrict__ x,
                                                const float* __restrict__ g,
                                                const float* __restrict__ bb,
                                                float* __restrict__ h,
                                                float* __restrict__ hn) {
  __shared__ float tmp[4];
  int row = blockIdx.x, t = threadIdx.x;
  size_t base = (size_t)row * E_DIM;
  float v0 = x[base + t], v1 = x[base + t + 256];
  float n = sqrtf(blockSum256(v0 * v0 + v1 * v1, tmp) + 1e-30f);
  float a = atanhf(fminf(n, MAXN)) / n;
  v0 *= a; v1 *= a;
  float mu = blockSum256(v0 + v1, tmp) * (1.f / 512.f);
  float d0 = v0 - mu, d1 = v1 - mu;
  float var = blockSum256(d0 * d0 + d1 * d1, tmp) * (1.f / 512.f);
  float rstd = 1.f / sqrtf(var + 1e-5f);
  v0 = d0 * rstd * g[t] + bb[t];
  v1 = d1 * rstd * g[t + 256] + bb[t + 256];
  float n2 = sqrtf(blockSum256(v0 * v0 + v1 * v1, tmp) + 1e-30f);
  float f = tanhf(n2) / n2;
  h[base + t] = v0 * f;
  h[base + t + 256] = v1 * f;
  if (t == 0) hn[row] = tanhf(n2);
}

// ---------------- fp32 GEMM: C[n][m] = sum_k A[n][k]*B[m][k] ----------------
// grid = (M/64, rows/64), block = 256.  BK = 32.
__global__ __launch_bounds__(256) void k_gemm(const float* __restrict__ A,
                                              const float* __restrict__ B,
                                              float* __restrict__ C, int K,
                                              int M) {
  __shared__ float As[32][68];
  __shared__ float Bs[32][68];
  int t = threadIdx.x;
  int tx = t & 15, ty = t >> 4;
  size_t arow0 = (size_t)blockIdx.y * 64;
  size_t bcol0 = (size_t)blockIdx.x * 64;
  int r0 = t >> 3;
  int kq = (t & 7) << 2;
  const float* pA0 = A + (arow0 + r0) * (size_t)K + kq;
  const float* pA1 = pA0 + (size_t)32 * K;
  const float* pB0 = B + (bcol0 + r0) * (size_t)K + kq;
  const float* pB1 = pB0 + (size_t)32 * K;
  float acc[4][4];
#pragma unroll
  for (int i = 0; i < 4; ++i)
#pragma unroll
    for (int j = 0; j < 4; ++j) acc[i][j] = 0.f;

  for (int kt = 0; kt < K; kt += 32) {
    float4 av0 = *reinterpret_cast<const float4*>(pA0 + kt);
    float4 av1 = *reinterpret_cast<const float4*>(pA1 + kt);
    float4 bv0 = *reinterpret_cast<const float4*>(pB0 + kt);
    float4 bv1 = *reinterpret_cast<const float4*>(pB1 + kt);
    __syncthreads();
    As[kq + 0][r0] = av0.x; As[kq + 1][r0] = av0.y;
    As[kq + 2][r0] = av0.z; As[kq + 3][r0] = av0.w;
    As[kq + 0][r0 + 32] = av1.x; As[kq + 1][r0 + 32] = av1.y;
    As[kq + 2][r0 + 32] = av1.z; As[kq + 3][r0 + 32] = av1.w;
    Bs[kq + 0][r0] = bv0.x; Bs[kq + 1][r0] = bv0.y;
    Bs[kq + 2][r0] = bv0.z; Bs[kq + 3][r0] = bv0.w;
    Bs[kq + 0][r0 + 32] = bv1.x; Bs[kq + 1][r0 + 32] = bv1.y;
    Bs[kq + 2][r0 + 32] = bv1.z; Bs[kq + 3][r0 + 32] = bv1.w;
    __syncthreads();
#pragma unroll
    for (int k = 0; k < 32; ++k) {
      float4 a4 = *reinterpret_cast<const float4*>(&As[k][ty << 2]);
      float4 b4 = *reinterpret_cast<const float4*>(&Bs[k][tx << 2]);
      float ar[4] = {a4.x, a4.y, a4.z, a4.w};
      float br[4] = {b4.x, b4.y, b4.z, b4.w};
#pragma unroll
      for (int i = 0; i < 4; ++i)
#pragma unroll
        for (int j = 0; j < 4; ++j) acc[i][j] += ar[i] * br[j];
    }
  }
  size_t crow = arow0 + (ty << 2);
  size_t ccol = bcol0 + (tx << 2);
#pragma unroll
  for (int i = 0; i < 4; ++i) {
    float4 v = make_float4(acc[i][0], acc[i][1], acc[i][2], acc[i][3]);
    *reinterpret_cast<float4*>(C + (crow + i) * (size_t)M + ccol) = v;
  }
}

// ---- QKV epilogue: q = logmap0(projx(mobius_add(matvec_scale(mx), bias))) --
__global__ __launch_bounds__(256) void k_epi_qkv(float* __restrict__ mx,
                                                 const float* __restrict__ xn_arr,
                                                 const float* __restrict__ bias) {
  __shared__ float tmp[4];
  int row = blockIdx.x, t = threadIdx.x;
  size_t base = (size_t)row * E_DIM;
  float m0 = mx[base + t], m1 = mx[base + t + 256];
  float bb0 = bias[t], bb1 = bias[t + 256];
  float mxn = sqrtf(blockSum256(m0 * m0 + m1 * m1, tmp) + 1e-30f);
  float xn = xn_arr[row];
  float aa = atanhf(fminf(xn, MAXN));
  float tt = tanhf(mxn / xn * aa);
  float c = tt / mxn;
  m0 *= c; m1 *= c;
  float xy = blockSum256(m0 * bb0 + m1 * bb1, tmp);
  float y2 = blockSum256(bb0 * bb0 + bb1 * bb1, tmp);
  float x2 = tt * tt;
  float c1 = 1.f + 2.f * xy + y2, c2 = 1.f - x2;
  float iden = 1.f / fmaxf(1.f + 2.f * xy + x2 * y2, 1e-15f);
  float u0 = (c1 * m0 + c2 * bb0) * iden, u1 = (c1 * m1 + c2 * bb1) * iden;
  float un = sqrtf(blockSum256(u0 * u0 + u1 * u1, tmp) + 1e-30f);
  float ps = un > MAXN ? MAXN / un : 1.f;
  float ne = fminf(un, MAXN);
  float f = ps * atanhf(ne) / ne;
  mx[base + t] = u0 * f;
  mx[base + t + 256] = u1 * f;
}

// ---- attention: per (b,h), online softmax; 1 query row/thread; IN-PLACE ---
// o aliases q: each thread reads its q row into registers before the barrier
// and writes only its own row at the end; K/V are read via LDS only.
__global__ __launch_bounds__(128) void k_attn(float* __restrict__ q,
                                              const float* __restrict__ k,
                                              const float* __restrict__ v) {
  __shared__ float Ks[128][64];
  __shared__ float Vs[128][64];
  int bh = blockIdx.x;
  int b = bh >> 3, h = bh & 7;
  int t = threadIdx.x;
  const size_t BE = (size_t)B_DIM * E_DIM;
  size_t base = (size_t)b * E_DIM + (size_t)h * 64;
  const float* kr = k + base + (size_t)t * BE;
  const float* vr = v + base + (size_t)t * BE;
#pragma unroll
  for (int d = 0; d < 64; d += 4) {
    *reinterpret_cast<float4*>(&Ks[t][d]) = *reinterpret_cast<const float4*>(kr + d);
    *reinterpret_cast<float4*>(&Vs[t][d]) = *reinterpret_cast<const float4*>(vr + d);
  }
  float qreg[64];
  float* qr = q + base + (size_t)t * BE;
#pragma unroll
  for (int d = 0; d < 64; d += 4) {
    float4 tq = *reinterpret_cast<const float4*>(qr + d);
    qreg[d] = tq.x; qreg[d + 1] = tq.y; qreg[d + 2] = tq.z; qreg[d + 3] = tq.w;
  }
  __syncthreads();
  float m = -1e30f, l = 0.f;
  float acc[64];
#pragma unroll
  for (int d = 0; d < 64; ++d) acc[d] = 0.f;
  for (int kk = 0; kk < 128; ++kk) {
    float s = 0.f;
#pragma unroll
    for (int d = 0; d < 64; d += 4) {
      float4 kv4 = *reinterpret_cast<const float4*>(&Ks[kk][d]);
      s += qreg[d] * kv4.x + qreg[d + 1] * kv4.y + qreg[d + 2] * kv4.z +
           qreg[d + 3] * kv4.w;
    }
    s *= 0.125f;
    if (s > m) {
      float corr = __expf(m - s);
      l *= corr;
#pragma unroll
      for (int d = 0; d < 64; ++d) acc[d] *= corr;
      m = s;
    }
    float p = __expf(s - m);
    l += p;
#pragma unroll
    for (int d = 0; d < 64; d += 4) {
      float4 vv4 = *reinterpret_cast<const float4*>(&Vs[kk][d]);
      acc[d] += p * vv4.x; acc[d + 1] += p * vv4.y;
      acc[d + 2] += p * vv4.z; acc[d + 3] += p * vv4.w;
    }
  }
  float inv = 1.f / l;
#pragma unroll
  for (int d = 0; d < 64; d += 4) {
    float4 vv = make_float4(acc[d] * inv, acc[d + 1] * inv, acc[d + 2] * inv,
                            acc[d + 3] * inv);
    *reinterpret_cast<float4*>(qr + d) = vv;
  }
}

// ---- expmap0 rowwise (attention out), save norm ---------------------------
__global__ __launch_bounds__(256) void k_expmap_rows(float* __restrict__ io,
                                                     float* __restrict__ nrm) {
  __shared__ float tmp[4];
  int row = blockIdx.x, t = threadIdx.x;
  size_t base = (size_t)row * E_DIM;
  float v0 = io[base + t], v1 = io[base + t + 256];
  float n = sqrtf(blockSum256(v0 * v0 + v1 * v1, tmp) + 1e-30f);
  float th = tanhf(n);
  float f = th / n;
  io[base + t] = v0 * f;
  io[base + t + 256] = v1 * f;
  if (t == 0) nrm[row] = th;
}

// ---- attn-out epilogue: man_linear(Wo) epi + residual mobius_add + LN2 ----
__global__ __launch_bounds__(256) void k_epi_attnout(
    float* __restrict__ mo, const float* __restrict__ xn_arr,
    const float* __restrict__ bo, const float* __restrict__ xin,
    const float* __restrict__ g2, const float* __restrict__ b2,
    float* __restrict__ h2, float* __restrict__ h2n) {
  __shared__ float tmp[4];
  int row = blockIdx.x, t = threadIdx.x;
  size_t base = (size_t)row * E_DIM;
  float m0 = mo[base + t], m1 = mo[base + t + 256];
  float bb0 = bo[t], bb1 = bo[t + 256];
  float mxn = sqrtf(blockSum256(m0 * m0 + m1 * m1, tmp) + 1e-30f);
  float xn = xn_arr[row];
  float aa = atanhf(fminf(xn, MAXN));
  float tt = tanhf(mxn / xn * aa);
  float c = tt / mxn;
  m0 *= c; m1 *= c;
  float xy = blockSum256(m0 * bb0 + m1 * bb1, tmp);
  float y2 = blockSum256(bb0 * bb0 + bb1 * bb1, tmp);
  float x2 = tt * tt;
  float c1 = 1.f + 2.f * xy + y2, c2 = 1.f - x2;
  float iden = 1.f / fmaxf(1.f + 2.f * xy + x2 * y2, 1e-15f);
  float u0 = (c1 * m0 + c2 * bb0) * iden, u1 = (c1 * m1 + c2 * bb1) * iden;
  float un = sqrtf(blockSum256(u0 * u0 + u1 * u1, tmp) + 1e-30f);
  float ps = un > MAXN ? MAXN / un : 1.f;
  float z0 = u0 * ps, z1 = u1 * ps;
  float zn = fminf(un, MAXN);
  float r0 = xin[base + t], r1 = xin[base + t + 256];
  float xy2 = blockSum256(z0 * r0 + z1 * r1, tmp);
  float y22 = blockSum256(r0 * r0 + r1 * r1, tmp);
  float x22 = zn * zn;
  float d1 = 1.f + 2.f * xy2 + y22, d2 = 1.f - x22;
  float iden2 = 1.f / fmaxf(1.f + 2.f * xy2 + x22 * y22, 1e-15f);
  float w0 = (d1 * z0 + d2 * r0) * iden2, w1 = (d1 * z1 + d2 * r1) * iden2;
  float wn = sqrtf(blockSum256(w0 * w0 + w1 * w1, tmp) + 1e-30f);
  float ps2 = wn > MAXN ? MAXN / wn : 1.f;
  w0 *= ps2; w1 *= ps2;
  mo[base + t] = w0;
  mo[base + t + 256] = w1;
  float ne = fminf(wn, MAXN);
  float lf = atanhf(ne) / ne;
  float l0 = w0 * lf, l1 = w1 * lf;
  float mu = blockSum256(l0 + l1, tmp) * (1.f / 512.f);
  float e0 = l0 - mu, e1 = l1 - mu;
  float var = blockSum256(e0 * e0 + e1 * e1, tmp) * (1.f / 512.f);
  float rstd = 1.f / sqrtf(var + 1e-5f);
  e0 = e0 * rstd * g2[t] + b2[t];
  e1 = e1 * rstd * g2[t + 256] + b2[t + 256];
  float n3 = sqrtf(blockSum256(e0 * e0 + e1 * e1, tmp) + 1e-30f);
  float en = tanhf(n3);
  float f = en / n3;
  if (en > MAXN) f *= MAXN / en;
  h2[base + t] = e0 * f;
  h2[base + t + 256] = e1 * f;
  if (t == 0) h2n[row] = fminf(en, MAXN);
}

// ---- FFN1 epilogue (rows of F=2048): man_linear epi + mob_relu, in-place --
__global__ __launch_bounds__(256) void k_epi_ffn1(float* __restrict__ m,
                                                  const float* __restrict__ xn_arr,
                                                  const float* __restrict__ bias,
                                                  float* __restrict__ hn_out) {
  __shared__ float tmp[4];
  int row = blockIdx.x, t = threadIdx.x;
  float* mr = m + (size_t)row * F_DIM;
  float mv[8], bvv[8];
  float p = 0.f;
#pragma unroll
  for (int i = 0; i < 8; ++i) {
    mv[i] = mr[t + i * 256];
    bvv[i] = bias[t + i * 256];
    p += mv[i] * mv[i];
  }
  float mxn = sqrtf(blockSum256(p, tmp) + 1e-30f);
  float xn = xn_arr[row];
  float aa = atanhf(fminf(xn, MAXN));
  float tt = tanhf(mxn / xn * aa);
  float c = tt / mxn;
  float pxy = 0.f, py2 = 0.f;
#pragma unroll
  for (int i = 0; i < 8; ++i) {
    mv[i] *= c;
    pxy += mv[i] * bvv[i];
    py2 += bvv[i] * bvv[i];
  }
  float xy = blockSum256(pxy, tmp);
  float y2 = blockSum256(py2, tmp);
  float x2 = tt * tt;
  float c1 = 1.f + 2.f * xy + y2, c2 = 1.f - x2;
  float iden = 1.f / fmaxf(1.f + 2.f * xy + x2 * y2, 1e-15f);
  float pu = 0.f;
#pragma unroll
  for (int i = 0; i < 8; ++i) {
    mv[i] = (c1 * mv[i] + c2 * bvv[i]) * iden;
    pu += mv[i] * mv[i];
  }
  float un = sqrtf(blockSum256(pu, tmp) + 1e-30f);
  float ps = un > MAXN ? MAXN / un : 1.f;
  float zn = fminf(un, MAXN);
  float lf = atanhf(zn) / zn * ps;
  float pr = 0.f;
#pragma unroll
  for (int i = 0; i < 8; ++i) {
    float l = fmaxf(mv[i] * lf, 0.f);
    mv[i] = l;
    pr += l * l;
  }
  float rn = sqrtf(blockSum256(pr, tmp) + 1e-30f);
  float en = tanhf(rn);
  float f = en / rn;
  if (en > MAXN) f *= MAXN / en;
#pragma unroll
  for (int i = 0; i < 8; ++i) mr[t + i * 256] = mv[i] * f;
  if (t == 0) hn_out[row] = fminf(en, MAXN);
}

// ---- final epilogue: man_linear(W2) epi + mob_relu + residual add + projx -
__global__ __launch_bounds__(256) void k_epi_final(
    const float* __restrict__ m2, const float* __restrict__ xn_arr,
    const float* __restrict__ bias, const float* __restrict__ res,
    float* __restrict__ out) {
  __shared__ float tmp[4];
  int row = blockIdx.x, t = threadIdx.x;
  size_t base = (size_t)row * E_DIM;
  float m0 = m2[base + t], m1 = m2[base + t + 256];
  float bb0 = bias[t], bb1 = bias[t + 256];
  float mxn = sqrtf(blockSum256(m0 * m0 + m1 * m1, tmp) + 1e-30f);
  float xn = xn_arr[row];
  float aa = atanhf(fminf(xn, MAXN));
  float tt = tanhf(mxn / xn * aa);
  float c = tt / mxn;
  m0 *= c; m1 *= c;
  float xy = blockSum256(m0 * bb0 + m1 * bb1, tmp);
  float y2 = blockSum256(bb0 * bb0 + bb1 * bb1, tmp);
  float x2 = tt * tt;
  float c1 = 1.f + 2.f * xy + y2, c2 = 1.f - x2;
  float iden = 1.f / fmaxf(1.f + 2.f * xy + x2 * y2, 1e-15f);
  float u0 = (c1 * m0 + c2 * bb0) * iden, u1 = (c1 * m1 + c2 * bb1) * iden;
  float un = sqrtf(blockSum256(u0 * u0 + u1 * u1, tmp) + 1e-30f);
  float ps = un > MAXN ? MAXN / un : 1.f;
  float zn = fminf(un, MAXN);
  float lf = atanhf(zn) / zn * ps;
  float r0 = fmaxf(u0 * lf, 0.f), r1 = fmaxf(u1 * lf, 0.f);
  float rn = sqrtf(blockSum256(r0 * r0 + r1 * r1, tmp) + 1e-30f);
  float en = tanhf(rn);
  float f = en / rn;
  if (en > MAXN) f *= MAXN / en;
  float h0 = r0 * f, h1 = r1 * f;
  float hn = fminf(en, MAXN);
  float q0 = res[base + t], q1 = res[base + t + 256];
  float xy2 = blockSum256(h0 * q0 + h1 * q1, tmp);
  float y22 = blockSum256(q0 * q0 + q1 * q1, tmp);
  float x22 = hn * hn;
  float d1 = 1.f + 2.f * xy2 + y22, d2 = 1.f - x22;
  float iden2 = 1.f / fmaxf(1.f + 2.f * xy2 + x22 * y22, 1e-15f);
  float w0 = (d1 * h0 + d2 * q0) * iden2, w1 = (d1 * h1 + d2 * q1) * iden2;
  float wn = sqrtf(blockSum256(w0 * w0 + w1 * w1, tmp) + 1e-30f);
  float ps2 = wn > MAXN ? MAXN / wn : 1.f;
  out[base + t] = w0 * ps2;
  out[base + t + 256] = w1 * ps2;
}

extern "C" void kernel_launch(void* const* d_in, const int* in_sizes, int n_in,
                              void* d_out, int out_size, void* d_ws,
                              size_t ws_size, hipStream_t stream) {
  const float* x   = (const float*)d_in[0];
  const float* g1  = (const float*)d_in[1];
  const float* lb1 = (const float*)d_in[2];
  const float* g2  = (const float*)d_in[3];
  const float* lb2 = (const float*)d_in[4];
  const float* Wq  = (const float*)d_in[5];
  const float* bq  = (const float*)d_in[6];
  const float* Wk  = (const float*)d_in[7];
  const float* bk  = (const float*)d_in[8];
  const float* Wv  = (const float*)d_in[9];
  const float* bv  = (const float*)d_in[10];
  const float* Wo  = (const float*)d_in[11];
  const float* bo  = (const float*)d_in[12];
  const float* W1  = (const float*)d_in[13];
  const float* b1  = (const float*)d_in[14];
  const float* W2  = (const float*)d_in[15];
  const float* b2  = (const float*)d_in[16];
  float* out = (float*)d_out;
  float* ws = (float*)d_ws;

  const size_t NE = (size_t)N_ROWS * E_DIM;  // 16,777,216 floats (64 MB)
  const size_t CE = (size_t)CH * E_DIM;      // 4,194,304 floats  (16 MB)
  // Peak-liveness layout (~208.5 MB):
  float* bufQ = ws;                 // mq/q -> attn-out -> oe -> [FFN hidden]
  float* bufK = ws + NE;            // mk/k -> mo -> res2
  float* bufV = ws + 2 * NE;        // mv/v -> h2
  float* bufC = ws + 3 * NE;        // h1 chunk, later m2 chunk
  float* n_h1 = bufC + CE;
  float* n_oe = n_h1 + N_ROWS;
  float* n_h2 = n_oe + N_ROWS;
  float* n_h3 = n_h2 + N_ROWS;
  const size_t need_bytes = (3 * NE + CE + 4 * (size_t)N_ROWS) * sizeof(float);
  if (ws_size < need_bytes) return;  // diagnostic: clean absmax-fail, not a fault

  // Phase A (chunked): h1 = expmap0(LN(logmap0(x)));  mq/mk/mv = h1 @ W^T;
  // then man_linear epilogue + logmap0 -> q,k,v.
  for (int c = 0; c < N_ROWS / CH; ++c) {
    size_t ro = (size_t)c * CH;
    k_stage1<<<CH, 256, 0, stream>>>(x + ro * E_DIM, g1, lb1, bufC, n_h1 + ro);
    dim3 gE(E_DIM / 64, CH / 64);
    k_gemm<<<gE, 256, 0, stream>>>(bufC, Wq, bufQ + ro * E_DIM, E_DIM, E_DIM);
    k_gemm<<<gE, 256, 0, stream>>>(bufC, Wk, bufK + ro * E_DIM, E_DIM, E_DIM);
    k_gemm<<<gE, 256, 0, stream>>>(bufC, Wv, bufV + ro * E_DIM, E_DIM, E_DIM);
    k_epi_qkv<<<CH, 256, 0, stream>>>(bufQ + ro * E_DIM, n_h1 + ro, bq);
    k_epi_qkv<<<CH, 256, 0, stream>>>(bufK + ro * E_DIM, n_h1 + ro, bk);
    k_epi_qkv<<<CH, 256, 0, stream>>>(bufV + ro * E_DIM, n_h1 + ro, bv);
  }

  // Phase B: attention (in-place over Q), then expmap0 rows.
  k_attn<<<B_DIM * 8, 128, 0, stream>>>(bufQ, bufK, bufV);
  k_expmap_rows<<<N_ROWS, 256, 0, stream>>>(bufQ, n_oe);

  // Phase C: Wo projection (-> bufK, K dead) + residual/LN2 epilogue.
  dim3 gO(E_DIM / 64, N_ROWS / 64);
  k_gemm<<<gO, 256, 0, stream>>>(bufQ, Wo, bufK, E_DIM, E_DIM);
  k_epi_attnout<<<N_ROWS, 256, 0, stream>>>(bufK, n_oe, bo, x, g2, lb2, bufV,
                                            n_h2);
  // now: bufK = res2, bufV = h2, bufQ dead.

  // Phase D (chunked): FFN. hidden -> bufQ (CH*F == NE floats), m2 -> bufC.
  for (int c = 0; c < N_ROWS / CH; ++c) {
    size_t ro = (size_t)c * CH;
    k_gemm<<<dim3(F_DIM / 64, CH / 64), 256, 0, stream>>>(
        bufV + ro * E_DIM, W1, bufQ, E_DIM, F_DIM);
    k_epi_ffn1<<<CH, 256, 0, stream>>>(bufQ, n_h2 + ro, b1, n_h3 + ro);
    k_gemm<<<dim3(E_DIM / 64, CH / 64), 256, 0, stream>>>(bufQ, W2, bufC,
                                                          F_DIM, E_DIM);
    k_epi_final<<<CH, 256, 0, stream>>>(bufC, n_h3 + ro, b2, bufK + ro * E_DIM,
                                        out + ro * E_DIM);
  }
}

// Round 3
// 1768.704 us; speedup vs baseline: 2.4102x; 2.4102x over previous
//
// Hyperbolic (Poincare ball) transformer block — MI355X round 3.
// bf16 MFMA GEMMs (m97 structure: 128x128 tile, 16x16x32 MFMA,
// global_load_lds width=16, contiguous LDS = conflict-free), bf16 attention
// inputs (fp32 math), fp32 norm bookkeeping to protect atanh-sensitive paths.
// FFN2 uses split-K=2 (blockIdx.z) to double its grid to 256 blocks.
// Workspace: 3*NE + weights(bf16) + norms = ~198.5 MB.
#include <hip/hip_runtime.h>
#include <math.h>

#define S_DIM 128
#define B_DIM 256
#define E_DIM 512
#define F_DIM 2048
#define N_ROWS (S_DIM * B_DIM) /* 32768 */
#define CH 4096                /* FFN row chunk */
#define MAXN 0.99999f          /* 1 - 1e-5 */

typedef __bf16 bf16x8 __attribute__((ext_vector_type(8)));
typedef float f32x4 __attribute__((ext_vector_type(4)));

__device__ __forceinline__ ushort f2bf(float f) {
  uint u = __float_as_uint(f);
  u += 0x7FFFu + ((u >> 16) & 1u);  // RNE
  return (ushort)(u >> 16);
}
__device__ __forceinline__ float bflo(uint u) { return __uint_as_float(u << 16); }
__device__ __forceinline__ float bfhi(uint u) { return __uint_as_float(u & 0xFFFF0000u); }

__device__ __forceinline__ void gld16(const ushort* g, ushort* l) {
  __builtin_amdgcn_global_load_lds(
      (const __attribute__((address_space(1))) void*)g,
      (__attribute__((address_space(3))) void*)l, 16, 0, 0);
}

// ---------------- fp32 -> bf16 convert (weights) ---------------------------
__global__ __launch_bounds__(256) void k_f2bf(const float* __restrict__ in,
                                              ushort* __restrict__ out, int n) {
  for (int i = blockIdx.x * 256 + threadIdx.x; i < n; i += gridDim.x * 256)
    out[i] = f2bf(in[i]);
}

// ---------------- block-wide sum over 256 threads (4 waves) ----------------
__device__ __forceinline__ float blockSum256(float v, float* tmp) {
#pragma unroll
  for (int o = 32; o > 0; o >>= 1) v += __shfl_down(v, o);
  int lane = threadIdx.x & 63, wid = threadIdx.x >> 6;
  if (lane == 0) tmp[wid] = v;
  __syncthreads();
  if (threadIdx.x == 0) tmp[0] = tmp[0] + tmp[1] + tmp[2] + tmp[3];
  __syncthreads();
  float r = tmp[0];
  __syncthreads();
  return r;
}

// ---- stage 1: h1 = expmap0(LN(logmap0(x))) -> bf16, save |h1| fp32 --------
__global__ __launch_bounds__(256) void k_stage1(const float* __restrict__ x,
                                                const float* __restrict__ g,
                                                const float* __restrict__ bb,
                                                ushort* __restrict__ h,
                                                float* __restrict__ hn) {
  __shared__ float tmp[4];
  int row = blockIdx.x, t = threadIdx.x;
  size_t base = (size_t)row * E_DIM;
  float v0 = x[base + t], v1 = x[base + t + 256];
  float n = sqrtf(blockSum256(v0 * v0 + v1 * v1, tmp) + 1e-30f);
  float a = atanhf(fminf(n, MAXN)) / n;
  v0 *= a; v1 *= a;
  float mu = blockSum256(v0 + v1, tmp) * (1.f / 512.f);
  float d0 = v0 - mu, d1 = v1 - mu;
  float var = blockSum256(d0 * d0 + d1 * d1, tmp) * (1.f / 512.f);
  float rstd = 1.f / sqrtf(var + 1e-5f);
  v0 = d0 * rstd * g[t] + bb[t];
  v1 = d1 * rstd * g[t + 256] + bb[t + 256];
  float n2 = sqrtf(blockSum256(v0 * v0 + v1 * v1, tmp) + 1e-30f);
  float f = tanhf(n2) / n2;
  h[base + t] = f2bf(v0 * f);
  h[base + t + 256] = f2bf(v1 * f);
  if (t == 0) hn[row] = tanhf(n2);
}

// -------- bf16 MFMA GEMM: C[n][m] = sum_k A[n][k]*B[m][k], C fp32 ----------
// A: rows x K bf16 row-major, B: M x K bf16 row-major.
// grid (M/128, rows/128, splits); block 256 = 4 waves in 2x2 of 64x64 tiles.
// kseg = K per z-slice; z writes C + z*partStride.
__global__ __launch_bounds__(256) void k_gemm_bf16(
    const ushort* __restrict__ A, const ushort* __restrict__ B,
    float* __restrict__ C, int K, int M, int kseg,
    unsigned long long partStride) {
  __shared__ __align__(16) ushort As[128 * 32];
  __shared__ __align__(16) ushort Bs[128 * 32];
  int tid = threadIdx.x;
  int w = tid >> 6, lane = tid & 63;
  int wm = w >> 1, wn = w & 1;
  size_t row0 = (size_t)blockIdx.y * 128;
  size_t col0 = (size_t)blockIdx.x * 128;
  int k0 = blockIdx.z * kseg;

  // staging: wave w covers 32 tile-rows via 2 insts of 16 rows (contiguous 1KB)
  const ushort* gA =
      A + (row0 + w * 32 + (lane >> 2)) * (size_t)K + (lane & 3) * 8 + k0;
  const ushort* gB =
      B + (col0 + w * 32 + (lane >> 2)) * (size_t)K + (lane & 3) * 8 + k0;
  ushort* lA = As + (w * 32) * 32;
  ushort* lB = Bs + (w * 32) * 32;
  const int rowK16 = 16 * K;

  // fragment read base: A[m=lane&15][k=(lane>>4)*8+j]
  int fro = (lane & 15) * 32 + (lane >> 4) * 8;
  const ushort* raA = As + (wm * 64) * 32 + fro;
  const ushort* raB = Bs + (wn * 64) * 32 + fro;

  f32x4 zero = {0.f, 0.f, 0.f, 0.f};
  f32x4 acc[4][4];
#pragma unroll
  for (int i = 0; i < 4; ++i)
#pragma unroll
    for (int j = 0; j < 4; ++j) acc[i][j] = zero;

  for (int kt = 0; kt < kseg; kt += 32) {
    __syncthreads();
    gld16(gA + kt, lA);
    gld16(gA + kt + rowK16, lA + 16 * 32);
    gld16(gB + kt, lB);
    gld16(gB + kt + rowK16, lB + 16 * 32);
    __syncthreads();
    bf16x8 af[4], bfv[4];
#pragma unroll
    for (int t = 0; t < 4; ++t) {
      af[t] = *reinterpret_cast<const bf16x8*>(raA + t * 512);
      bfv[t] = *reinterpret_cast<const bf16x8*>(raB + t * 512);
    }
#pragma unroll
    for (int i = 0; i < 4; ++i)
#pragma unroll
      for (int j = 0; j < 4; ++j)
        acc[i][j] = __builtin_amdgcn_mfma_f32_16x16x32_bf16(af[i], bfv[j],
                                                            acc[i][j], 0, 0, 0);
  }
  float* Cz = C + (size_t)blockIdx.z * partStride;
  int crow = wm * 64 + (lane >> 4) * 4;  // + ti*16 + reg
  int ccol = (int)col0 + wn * 64 + (lane & 15);
#pragma unroll
  for (int ti = 0; ti < 4; ++ti) {
    size_t r = row0 + crow + ti * 16;
#pragma unroll
    for (int tj = 0; tj < 4; ++tj) {
      int cc = ccol + tj * 16;
#pragma unroll
      for (int reg = 0; reg < 4; ++reg)
        Cz[(r + reg) * (size_t)M + cc] = acc[ti][tj][reg];
    }
  }
}

// ---- QKV epilogue: q = logmap0(projx(mobius_add(mv(mx), bias))) -> bf16 ---
__global__ __launch_bounds__(256) void k_epi_qkv(const float* __restrict__ mx,
                                                 const float* __restrict__ xn_arr,
                                                 const float* __restrict__ bias,
                                                 ushort* __restrict__ qout) {
  __shared__ float tmp[4];
  int row = blockIdx.x, t = threadIdx.x;
  size_t base = (size_t)row * E_DIM;
  float m0 = mx[base + t], m1 = mx[base + t + 256];
  float bb0 = bias[t], bb1 = bias[t + 256];
  float mxn = sqrtf(blockSum256(m0 * m0 + m1 * m1, tmp) + 1e-30f);
  float xn = xn_arr[row];
  float aa = atanhf(fminf(xn, MAXN));
  float tt = tanhf(mxn / xn * aa);
  float c = tt / mxn;
  m0 *= c; m1 *= c;
  float xy = blockSum256(m0 * bb0 + m1 * bb1, tmp);
  float y2 = blockSum256(bb0 * bb0 + bb1 * bb1, tmp);
  float x2 = tt * tt;
  float c1 = 1.f + 2.f * xy + y2, c2 = 1.f - x2;
  float iden = 1.f / fmaxf(1.f + 2.f * xy + x2 * y2, 1e-15f);
  float u0 = (c1 * m0 + c2 * bb0) * iden, u1 = (c1 * m1 + c2 * bb1) * iden;
  float un = sqrtf(blockSum256(u0 * u0 + u1 * u1, tmp) + 1e-30f);
  float ps = un > MAXN ? MAXN / un : 1.f;
  float ne = fminf(un, MAXN);
  float f = ps * atanhf(ne) / ne;
  qout[base + t] = f2bf(u0 * f);
  qout[base + t + 256] = f2bf(u1 * f);
}

// ---- attention: per (b,h); bf16 K/V/Q in LDS/regs, fp32 math, fp32 out ----
__global__ __launch_bounds__(128) void k_attn(const ushort* __restrict__ q,
                                              const ushort* __restrict__ k,
                                              const ushort* __restrict__ v,
                                              float* __restrict__ o) {
  __shared__ ushort Ks[128][64];
  __shared__ ushort Vs[128][64];
  int bh = blockIdx.x;
  int b = bh >> 3, h = bh & 7;
  int t = threadIdx.x;
  const size_t BE = (size_t)B_DIM * E_DIM;
  size_t base = (size_t)b * E_DIM + (size_t)h * 64;
  const ushort* kr = k + base + (size_t)t * BE;
  const ushort* vr = v + base + (size_t)t * BE;
#pragma unroll
  for (int j = 0; j < 8; ++j) {
    *reinterpret_cast<uint4*>(&Ks[t][j * 8]) =
        *reinterpret_cast<const uint4*>(kr + j * 8);
    *reinterpret_cast<uint4*>(&Vs[t][j * 8]) =
        *reinterpret_cast<const uint4*>(vr + j * 8);
  }
  float qreg[64];
  const ushort* qr = q + base + (size_t)t * BE;
#pragma unroll
  for (int j = 0; j < 8; ++j) {
    uint4 u = *reinterpret_cast<const uint4*>(qr + j * 8);
    qreg[j * 8 + 0] = bflo(u.x); qreg[j * 8 + 1] = bfhi(u.x);
    qreg[j * 8 + 2] = bflo(u.y); qreg[j * 8 + 3] = bfhi(u.y);
    qreg[j * 8 + 4] = bflo(u.z); qreg[j * 8 + 5] = bfhi(u.z);
    qreg[j * 8 + 6] = bflo(u.w); qreg[j * 8 + 7] = bfhi(u.w);
  }
  __syncthreads();
  float m = -1e30f, l = 0.f;
  float acc[64];
#pragma unroll
  for (int d = 0; d < 64; ++d) acc[d] = 0.f;
  for (int kk = 0; kk < 128; ++kk) {
    float s = 0.f;
#pragma unroll
    for (int j = 0; j < 8; ++j) {
      uint4 u = *reinterpret_cast<const uint4*>(&Ks[kk][j * 8]);
      s += qreg[j * 8 + 0] * bflo(u.x) + qreg[j * 8 + 1] * bfhi(u.x) +
           qreg[j * 8 + 2] * bflo(u.y) + qreg[j * 8 + 3] * bfhi(u.y) +
           qreg[j * 8 + 4] * bflo(u.z) + qreg[j * 8 + 5] * bfhi(u.z) +
           qreg[j * 8 + 6] * bflo(u.w) + qreg[j * 8 + 7] * bfhi(u.w);
    }
    s *= 0.125f;
    if (s > m) {
      float corr = __expf(m - s);
      l *= corr;
#pragma unroll
      for (int d = 0; d < 64; ++d) acc[d] *= corr;
      m = s;
    }
    float p = __expf(s - m);
    l += p;
#pragma unroll
    for (int j = 0; j < 8; ++j) {
      uint4 u = *reinterpret_cast<const uint4*>(&Vs[kk][j * 8]);
      acc[j * 8 + 0] += p * bflo(u.x); acc[j * 8 + 1] += p * bfhi(u.x);
      acc[j * 8 + 2] += p * bflo(u.y); acc[j * 8 + 3] += p * bfhi(u.y);
      acc[j * 8 + 4] += p * bflo(u.z); acc[j * 8 + 5] += p * bfhi(u.z);
      acc[j * 8 + 6] += p * bflo(u.w); acc[j * 8 + 7] += p * bfhi(u.w);
    }
  }
  float inv = 1.f / l;
  float* orow = o + base + (size_t)t * BE;
#pragma unroll
  for (int d = 0; d < 64; d += 4) {
    float4 vv = make_float4(acc[d] * inv, acc[d + 1] * inv, acc[d + 2] * inv,
                            acc[d + 3] * inv);
    *reinterpret_cast<float4*>(orow + d) = vv;
  }
}

// ---- expmap0 rowwise (attention out fp32 -> oe bf16), save norm -----------
__global__ __launch_bounds__(256) void k_expmap_rows(const float* __restrict__ in,
                                                     ushort* __restrict__ out,
                                                     float* __restrict__ nrm) {
  __shared__ float tmp[4];
  int row = blockIdx.x, t = threadIdx.x;
  size_t base = (size_t)row * E_DIM;
  float v0 = in[base + t], v1 = in[base + t + 256];
  float n = sqrtf(blockSum256(v0 * v0 + v1 * v1, tmp) + 1e-30f);
  float th = tanhf(n);
  float f = th / n;
  out[base + t] = f2bf(v0 * f);
  out[base + t + 256] = f2bf(v1 * f);
  if (t == 0) nrm[row] = th;
}

// ---- attn-out epilogue: man_linear(Wo) + residual mobius_add + LN2 --------
// res2 fp32 in-place over mo; h2 bf16 out.
__global__ __launch_bounds__(256) void k_epi_attnout(
    float* __restrict__ mo, const float* __restrict__ xn_arr,
    const float* __restrict__ bo, const float* __restrict__ xin,
    const float* __restrict__ g2, const float* __restrict__ b2,
    ushort* __restrict__ h2, float* __restrict__ h2n) {
  __shared__ float tmp[4];
  int row = blockIdx.x, t = threadIdx.x;
  size_t base = (size_t)row * E_DIM;
  float m0 = mo[base + t], m1 = mo[base + t + 256];
  float bb0 = bo[t], bb1 = bo[t + 256];
  float mxn = sqrtf(blockSum256(m0 * m0 + m1 * m1, tmp) + 1e-30f);
  float xn = xn_arr[row];
  float aa = atanhf(fminf(xn, MAXN));
  float tt = tanhf(mxn / xn * aa);
  float c = tt / mxn;
  m0 *= c; m1 *= c;
  float xy = blockSum256(m0 * bb0 + m1 * bb1, tmp);
  float y2 = blockSum256(bb0 * bb0 + bb1 * bb1, tmp);
  float x2 = tt * tt;
  float c1 = 1.f + 2.f * xy + y2, c2 = 1.f - x2;
  float iden = 1.f / fmaxf(1.f + 2.f * xy + x2 * y2, 1e-15f);
  float u0 = (c1 * m0 + c2 * bb0) * iden, u1 = (c1 * m1 + c2 * bb1) * iden;
  float un = sqrtf(blockSum256(u0 * u0 + u1 * u1, tmp) + 1e-30f);
  float ps = un > MAXN ? MAXN / un : 1.f;
  float z0 = u0 * ps, z1 = u1 * ps;
  float zn = fminf(un, MAXN);
  float r0 = xin[base + t], r1 = xin[base + t + 256];
  float xy2 = blockSum256(z0 * r0 + z1 * r1, tmp);
  float y22 = blockSum256(r0 * r0 + r1 * r1, tmp);
  float x22 = zn * zn;
  float d1 = 1.f + 2.f * xy2 + y22, d2 = 1.f - x22;
  float iden2 = 1.f / fmaxf(1.f + 2.f * xy2 + x22 * y22, 1e-15f);
  float w0 = (d1 * z0 + d2 * r0) * iden2, w1 = (d1 * z1 + d2 * r1) * iden2;
  float wn = sqrtf(blockSum256(w0 * w0 + w1 * w1, tmp) + 1e-30f);
  float ps2 = wn > MAXN ? MAXN / wn : 1.f;
  w0 *= ps2; w1 *= ps2;
  mo[base + t] = w0;
  mo[base + t + 256] = w1;
  float ne = fminf(wn, MAXN);
  float lf = atanhf(ne) / ne;
  float l0 = w0 * lf, l1 = w1 * lf;
  float mu = blockSum256(l0 + l1, tmp) * (1.f / 512.f);
  float e0 = l0 - mu, e1 = l1 - mu;
  float var = blockSum256(e0 * e0 + e1 * e1, tmp) * (1.f / 512.f);
  float rstd = 1.f / sqrtf(var + 1e-5f);
  e0 = e0 * rstd * g2[t] + b2[t];
  e1 = e1 * rstd * g2[t + 256] + b2[t + 256];
  float n3 = sqrtf(blockSum256(e0 * e0 + e1 * e1, tmp) + 1e-30f);
  float en = tanhf(n3);
  float f = en / n3;
  if (en > MAXN) f *= MAXN / en;
  h2[base + t] = f2bf(e0 * f);
  h2[base + t + 256] = f2bf(e1 * f);
  if (t == 0) h2n[row] = fminf(en, MAXN);
}

// ---- FFN1 epilogue (rows of F): man_linear epi + mob_relu -> bf16 ---------
__global__ __launch_bounds__(256) void k_epi_ffn1(const float* __restrict__ m,
                                                  const float* __restrict__ xn_arr,
                                                  const float* __restrict__ bias,
                                                  ushort* __restrict__ hid,
                                                  float* __restrict__ hn_out) {
  __shared__ float tmp[4];
  int row = blockIdx.x, t = threadIdx.x;
  const float* mr = m + (size_t)row * F_DIM;
  ushort* hr = hid + (size_t)row * F_DIM;
  float mv[8], bvv[8];
  float p = 0.f;
#pragma unroll
  for (int i = 0; i < 8; ++i) {
    mv[i] = mr[t + i * 256];
    bvv[i] = bias[t + i * 256];
    p += mv[i] * mv[i];
  }
  float mxn = sqrtf(blockSum256(p, tmp) + 1e-30f);
  float xn = xn_arr[row];
  float aa = atanhf(fminf(xn, MAXN));
  float tt = tanhf(mxn / xn * aa);
  float c = tt / mxn;
  float pxy = 0.f, py2 = 0.f;
#pragma unroll
  for (int i = 0; i < 8; ++i) {
    mv[i] *= c;
    pxy += mv[i] * bvv[i];
    py2 += bvv[i] * bvv[i];
  }
  float xy = blockSum256(pxy, tmp);
  float y2 = blockSum256(py2, tmp);
  float x2 = tt * tt;
  float c1 = 1.f + 2.f * xy + y2, c2 = 1.f - x2;
  float iden = 1.f / fmaxf(1.f + 2.f * xy + x2 * y2, 1e-15f);
  float pu = 0.f;
#pragma unroll
  for (int i = 0; i < 8; ++i) {
    mv[i] = (c1 * mv[i] + c2 * bvv[i]) * iden;
    pu += mv[i] * mv[i];
  }
  float un = sqrtf(blockSum256(pu, tmp) + 1e-30f);
  float ps = un > MAXN ? MAXN / un : 1.f;
  float zn = fminf(un, MAXN);
  float lf = atanhf(zn) / zn * ps;
  float pr = 0.f;
#pragma unroll
  for (int i = 0; i < 8; ++i) {
    float l = fmaxf(mv[i] * lf, 0.f);
    mv[i] = l;
    pr += l * l;
  }
  float rn = sqrtf(blockSum256(pr, tmp) + 1e-30f);
  float en = tanhf(rn);
  float f = en / rn;
  if (en > MAXN) f *= MAXN / en;
#pragma unroll
  for (int i = 0; i < 8; ++i) hr[t + i * 256] = f2bf(mv[i] * f);
  if (t == 0) hn_out[row] = fminf(en, MAXN);
}

// ---- final epilogue: sum split-K partials + man_linear(W2) + mob_relu +
// residual mobius_add + projx ----------------------------------------------
__global__ __launch_bounds__(256) void k_epi_final(
    const float* __restrict__ m2a, const float* __restrict__ m2b,
    const float* __restrict__ xn_arr, const float* __restrict__ bias,
    const float* __restrict__ res, float* __restrict__ out) {
  __shared__ float tmp[4];
  int row = blockIdx.x, t = threadIdx.x;
  size_t base = (size_t)row * E_DIM;
  float m0 = m2a[base + t] + m2b[base + t];
  float m1 = m2a[base + t + 256] + m2b[base + t + 256];
  float bb0 = bias[t], bb1 = bias[t + 256];
  float mxn = sqrtf(blockSum256(m0 * m0 + m1 * m1, tmp) + 1e-30f);
  float xn = xn_arr[row];
  float aa = atanhf(fminf(xn, MAXN));
  float tt = tanhf(mxn / xn * aa);
  float c = tt / mxn;
  m0 *= c; m1 *= c;
  float xy = blockSum256(m0 * bb0 + m1 * bb1, tmp);
  float y2 = blockSum256(bb0 * bb0 + bb1 * bb1, tmp);
  float x2 = tt * tt;
  float c1 = 1.f + 2.f * xy + y2, c2 = 1.f - x2;
  float iden = 1.f / fmaxf(1.f + 2.f * xy + x2 * y2, 1e-15f);
  float u0 = (c1 * m0 + c2 * bb0) * iden, u1 = (c1 * m1 + c2 * bb1) * iden;
  float un = sqrtf(blockSum256(u0 * u0 + u1 * u1, tmp) + 1e-30f);
  float ps = un > MAXN ? MAXN / un : 1.f;
  float zn = fminf(un, MAXN);
  float lf = atanhf(zn) / zn * ps;
  float r0 = fmaxf(u0 * lf, 0.f), r1 = fmaxf(u1 * lf, 0.f);
  float rn = sqrtf(blockSum256(r0 * r0 + r1 * r1, tmp) + 1e-30f);
  float en = tanhf(rn);
  float f = en / rn;
  if (en > MAXN) f *= MAXN / en;
  float h0 = r0 * f, h1 = r1 * f;
  float hn = fminf(en, MAXN);
  float q0 = res[base + t], q1 = res[base + t + 256];
  float xy2 = blockSum256(h0 * q0 + h1 * q1, tmp);
  float y22 = blockSum256(q0 * q0 + q1 * q1, tmp);
  float x22 = hn * hn;
  float d1 = 1.f + 2.f * xy2 + y22, d2 = 1.f - x22;
  float iden2 = 1.f / fmaxf(1.f + 2.f * xy2 + x22 * y22, 1e-15f);
  float w0 = (d1 * h0 + d2 * q0) * iden2, w1 = (d1 * h1 + d2 * q1) * iden2;
  float wn = sqrtf(blockSum256(w0 * w0 + w1 * w1, tmp) + 1e-30f);
  float ps2 = wn > MAXN ? MAXN / wn : 1.f;
  out[base + t] = w0 * ps2;
  out[base + t + 256] = w1 * ps2;
}

extern "C" void kernel_launch(void* const* d_in, const int* in_sizes, int n_in,
                              void* d_out, int out_size, void* d_ws,
                              size_t ws_size, hipStream_t stream) {
  const float* x   = (const float*)d_in[0];
  const float* g1  = (const float*)d_in[1];
  const float* lb1 = (const float*)d_in[2];
  const float* g2  = (const float*)d_in[3];
  const float* lb2 = (const float*)d_in[4];
  const float* Wq  = (const float*)d_in[5];
  const float* bq  = (const float*)d_in[6];
  const float* Wk  = (const float*)d_in[7];
  const float* bk  = (const float*)d_in[8];
  const float* Wv  = (const float*)d_in[9];
  const float* bv  = (const float*)d_in[10];
  const float* Wo  = (const float*)d_in[11];
  const float* bo  = (const float*)d_in[12];
  const float* W1  = (const float*)d_in[13];
  const float* b1  = (const float*)d_in[14];
  const float* W2  = (const float*)d_in[15];
  const float* b2  = (const float*)d_in[16];
  float* out = (float*)d_out;
  float* ws = (float*)d_ws;

  const size_t NE = (size_t)N_ROWS * E_DIM;          // 16,777,216
  const size_t WF = (4 * (size_t)E_DIM * E_DIM +
                     2 * (size_t)F_DIM * E_DIM) / 2; // 1,572,864 floats
  // Regions (floats):
  float* R_b = ws;                   // NE: mx fp32 / attn-out / mo / res2
  float* R_a = ws + NE;              // NE/2: h1_bf16 -> oe_bf16
  float* R_q = ws + NE + NE / 2;     // NE/2: q_bf16 -> h2_bf16
  float* R_k = ws + 2 * NE;          // NE/2: k_bf16 -> m1 fp32 (CH x F)
  float* R_v = ws + 2 * NE + NE / 2; // NE/2: v_bf16 -> hid_bf16 + m2 partials
  ushort* wqb = (ushort*)(ws + 3 * NE);
  ushort* wkb = wqb + (size_t)E_DIM * E_DIM;
  ushort* wvb = wkb + (size_t)E_DIM * E_DIM;
  ushort* wob = wvb + (size_t)E_DIM * E_DIM;
  ushort* w1b = wob + (size_t)E_DIM * E_DIM;
  ushort* w2b = w1b + (size_t)F_DIM * E_DIM;
  float* n_h1 = ws + 3 * NE + WF;
  float* n_oe = n_h1 + N_ROWS;
  float* n_h2 = n_oe + N_ROWS;
  float* n_h3 = n_h2 + N_ROWS;
  const size_t need = (3 * NE + WF + 4 * (size_t)N_ROWS) * sizeof(float);
  if (ws_size < need) return;  // clean absmax-fail instead of device fault

  // Weight conversion fp32 -> bf16
  k_f2bf<<<256, 256, 0, stream>>>(Wq, wqb, E_DIM * E_DIM);
  k_f2bf<<<256, 256, 0, stream>>>(Wk, wkb, E_DIM * E_DIM);
  k_f2bf<<<256, 256, 0, stream>>>(Wv, wvb, E_DIM * E_DIM);
  k_f2bf<<<256, 256, 0, stream>>>(Wo, wob, E_DIM * E_DIM);
  k_f2bf<<<512, 256, 0, stream>>>(W1, w1b, F_DIM * E_DIM);
  k_f2bf<<<512, 256, 0, stream>>>(W2, w2b, F_DIM * E_DIM);

  ushort* h1b = (ushort*)R_a;
  ushort* qb = (ushort*)R_q;
  ushort* kb = (ushort*)R_k;
  ushort* vb = (ushort*)R_v;

  // Phase A: stage1 + QKV projections
  k_stage1<<<N_ROWS, 256, 0, stream>>>(x, g1, lb1, h1b, n_h1);
  dim3 gQ(E_DIM / 128, N_ROWS / 128, 1);
  k_gemm_bf16<<<gQ, 256, 0, stream>>>(h1b, wqb, R_b, E_DIM, E_DIM, E_DIM, 0);
  k_epi_qkv<<<N_ROWS, 256, 0, stream>>>(R_b, n_h1, bq, qb);
  k_gemm_bf16<<<gQ, 256, 0, stream>>>(h1b, wkb, R_b, E_DIM, E_DIM, E_DIM, 0);
  k_epi_qkv<<<N_ROWS, 256, 0, stream>>>(R_b, n_h1, bk, kb);
  k_gemm_bf16<<<gQ, 256, 0, stream>>>(h1b, wvb, R_b, E_DIM, E_DIM, E_DIM, 0);
  k_epi_qkv<<<N_ROWS, 256, 0, stream>>>(R_b, n_h1, bv, vb);

  // Phase B: attention -> R_b fp32; expmap0 -> oe bf16 (R_a, h1 dead)
  k_attn<<<B_DIM * 8, 128, 0, stream>>>(qb, kb, vb, R_b);
  ushort* oeb = (ushort*)R_a;
  k_expmap_rows<<<N_ROWS, 256, 0, stream>>>(R_b, oeb, n_oe);

  // Phase C: Wo projection -> R_b (attn-out consumed); epilogue:
  // res2 in-place R_b, h2 bf16 -> R_q (q dead)
  ushort* h2b = (ushort*)R_q;
  k_gemm_bf16<<<gQ, 256, 0, stream>>>(oeb, wob, R_b, E_DIM, E_DIM, E_DIM, 0);
  k_epi_attnout<<<N_ROWS, 256, 0, stream>>>(R_b, n_oe, bo, x, g2, lb2, h2b,
                                            n_h2);

  // Phase D: FFN chunked (CH rows). m1 fp32 -> R_k (k dead, CHxF = NE/2 fl);
  // hidden bf16 -> R_v[0, NE/4); m2 partials -> R_v[NE/4, NE/2).
  float* m1 = R_k;
  ushort* hidb = (ushort*)R_v;
  float* m2p = R_v + NE / 4;                   // 2 partials of CH*E floats
  const unsigned long long pstr = (unsigned long long)CH * E_DIM;
  for (int c = 0; c < N_ROWS / CH; ++c) {
    size_t ro = (size_t)c * CH;
    k_gemm_bf16<<<dim3(F_DIM / 128, CH / 128, 1), 256, 0, stream>>>(
        h2b + ro * E_DIM, w1b, m1, E_DIM, F_DIM, E_DIM, 0);
    k_epi_ffn1<<<CH, 256, 0, stream>>>(m1, n_h2 + ro, b1, hidb, n_h3 + ro);
    k_gemm_bf16<<<dim3(E_DIM / 128, CH / 128, 2), 256, 0, stream>>>(
        hidb, w2b, m2p, F_DIM, E_DIM, F_DIM / 2, pstr);
    k_epi_final<<<CH, 256, 0, stream>>>(m2p, m2p + pstr, n_h3 + ro, b2,
                                        R_b + ro * E_DIM, out + ro * E_DIM);
  }
}

// Round 4
// 1566.080 us; speedup vs baseline: 2.7220x; 1.1294x over previous
//
// Hyperbolic (Poincare ball) transformer block — MI355X round 4.
// Round-3 + MFMA flash-style attention: per-(b,h) 128x128 tile, QK^T and PV
// via mfma_16x16x32_bf16, register softmax with __shfl_xor over 16-lane key
// groups, P round-trips LDS (overlays dead Q/K) into A-operand layout.
// LDS 54.3 KB -> 3 blocks/CU. GEMMs unchanged (m97 structure, passing).
#include <hip/hip_runtime.h>
#include <math.h>

#define S_DIM 128
#define B_DIM 256
#define E_DIM 512
#define F_DIM 2048
#define N_ROWS (S_DIM * B_DIM) /* 32768 */
#define CH 4096                /* FFN row chunk */
#define MAXN 0.99999f          /* 1 - 1e-5 */

typedef __bf16 bf16x8 __attribute__((ext_vector_type(8)));
typedef float f32x4 __attribute__((ext_vector_type(4)));

__device__ __forceinline__ ushort f2bf(float f) {
  uint u = __float_as_uint(f);
  u += 0x7FFFu + ((u >> 16) & 1u);  // RNE
  return (ushort)(u >> 16);
}

__device__ __forceinline__ void gld16(const ushort* g, ushort* l) {
  __builtin_amdgcn_global_load_lds(
      (const __attribute__((address_space(1))) void*)g,
      (__attribute__((address_space(3))) void*)l, 16, 0, 0);
}

// ---------------- fp32 -> bf16 convert (weights) ---------------------------
__global__ __launch_bounds__(256) void k_f2bf(const float* __restrict__ in,
                                              ushort* __restrict__ out, int n) {
  for (int i = blockIdx.x * 256 + threadIdx.x; i < n; i += gridDim.x * 256)
    out[i] = f2bf(in[i]);
}

// ---------------- block-wide sum over 256 threads (4 waves) ----------------
__device__ __forceinline__ float blockSum256(float v, float* tmp) {
#pragma unroll
  for (int o = 32; o > 0; o >>= 1) v += __shfl_down(v, o);
  int lane = threadIdx.x & 63, wid = threadIdx.x >> 6;
  if (lane == 0) tmp[wid] = v;
  __syncthreads();
  if (threadIdx.x == 0) tmp[0] = tmp[0] + tmp[1] + tmp[2] + tmp[3];
  __syncthreads();
  float r = tmp[0];
  __syncthreads();
  return r;
}

// ---- stage 1: h1 = expmap0(LN(logmap0(x))) -> bf16, save |h1| fp32 --------
__global__ __launch_bounds__(256) void k_stage1(const float* __restrict__ x,
                                                const float* __restrict__ g,
                                                const float* __restrict__ bb,
                                                ushort* __restrict__ h,
                                                float* __restrict__ hn) {
  __shared__ float tmp[4];
  int row = blockIdx.x, t = threadIdx.x;
  size_t base = (size_t)row * E_DIM;
  float v0 = x[base + t], v1 = x[base + t + 256];
  float n = sqrtf(blockSum256(v0 * v0 + v1 * v1, tmp) + 1e-30f);
  float a = atanhf(fminf(n, MAXN)) / n;
  v0 *= a; v1 *= a;
  float mu = blockSum256(v0 + v1, tmp) * (1.f / 512.f);
  float d0 = v0 - mu, d1 = v1 - mu;
  float var = blockSum256(d0 * d0 + d1 * d1, tmp) * (1.f / 512.f);
  float rstd = 1.f / sqrtf(var + 1e-5f);
  v0 = d0 * rstd * g[t] + bb[t];
  v1 = d1 * rstd * g[t + 256] + bb[t + 256];
  float n2 = sqrtf(blockSum256(v0 * v0 + v1 * v1, tmp) + 1e-30f);
  float f = tanhf(n2) / n2;
  h[base + t] = f2bf(v0 * f);
  h[base + t + 256] = f2bf(v1 * f);
  if (t == 0) hn[row] = tanhf(n2);
}

// -------- bf16 MFMA GEMM: C[n][m] = sum_k A[n][k]*B[m][k], C fp32 ----------
__global__ __launch_bounds__(256) void k_gemm_bf16(
    const ushort* __restrict__ A, const ushort* __restrict__ B,
    float* __restrict__ C, int K, int M, int kseg,
    unsigned long long partStride) {
  __shared__ __align__(16) ushort As[128 * 32];
  __shared__ __align__(16) ushort Bs[128 * 32];
  int tid = threadIdx.x;
  int w = tid >> 6, lane = tid & 63;
  int wm = w >> 1, wn = w & 1;
  size_t row0 = (size_t)blockIdx.y * 128;
  size_t col0 = (size_t)blockIdx.x * 128;
  int k0 = blockIdx.z * kseg;

  const ushort* gA =
      A + (row0 + w * 32 + (lane >> 2)) * (size_t)K + (lane & 3) * 8 + k0;
  const ushort* gB =
      B + (col0 + w * 32 + (lane >> 2)) * (size_t)K + (lane & 3) * 8 + k0;
  ushort* lA = As + (w * 32) * 32;
  ushort* lB = Bs + (w * 32) * 32;
  const int rowK16 = 16 * K;

  int fro = (lane & 15) * 32 + (lane >> 4) * 8;
  const ushort* raA = As + (wm * 64) * 32 + fro;
  const ushort* raB = Bs + (wn * 64) * 32 + fro;

  f32x4 zero = {0.f, 0.f, 0.f, 0.f};
  f32x4 acc[4][4];
#pragma unroll
  for (int i = 0; i < 4; ++i)
#pragma unroll
    for (int j = 0; j < 4; ++j) acc[i][j] = zero;

  for (int kt = 0; kt < kseg; kt += 32) {
    __syncthreads();
    gld16(gA + kt, lA);
    gld16(gA + kt + rowK16, lA + 16 * 32);
    gld16(gB + kt, lB);
    gld16(gB + kt + rowK16, lB + 16 * 32);
    __syncthreads();
    bf16x8 af[4], bfv[4];
#pragma unroll
    for (int t = 0; t < 4; ++t) {
      af[t] = *reinterpret_cast<const bf16x8*>(raA + t * 512);
      bfv[t] = *reinterpret_cast<const bf16x8*>(raB + t * 512);
    }
#pragma unroll
    for (int i = 0; i < 4; ++i)
#pragma unroll
      for (int j = 0; j < 4; ++j)
        acc[i][j] = __builtin_amdgcn_mfma_f32_16x16x32_bf16(af[i], bfv[j],
                                                            acc[i][j], 0, 0, 0);
  }
  float* Cz = C + (size_t)blockIdx.z * partStride;
  int crow = wm * 64 + (lane >> 4) * 4;
  int ccol = (int)col0 + wn * 64 + (lane & 15);
#pragma unroll
  for (int ti = 0; ti < 4; ++ti) {
    size_t r = row0 + crow + ti * 16;
#pragma unroll
    for (int tj = 0; tj < 4; ++tj) {
      int cc = ccol + tj * 16;
#pragma unroll
      for (int reg = 0; reg < 4; ++reg)
        Cz[(r + reg) * (size_t)M + cc] = acc[ti][tj][reg];
    }
  }
}

// ---- QKV epilogue: q = logmap0(projx(mobius_add(mv(mx), bias))) -> bf16 ---
__global__ __launch_bounds__(256) void k_epi_qkv(const float* __restrict__ mx,
                                                 const float* __restrict__ xn_arr,
                                                 const float* __restrict__ bias,
                                                 ushort* __restrict__ qout) {
  __shared__ float tmp[4];
  int row = blockIdx.x, t = threadIdx.x;
  size_t base = (size_t)row * E_DIM;
  float m0 = mx[base + t], m1 = mx[base + t + 256];
  float bb0 = bias[t], bb1 = bias[t + 256];
  float mxn = sqrtf(blockSum256(m0 * m0 + m1 * m1, tmp) + 1e-30f);
  float xn = xn_arr[row];
  float aa = atanhf(fminf(xn, MAXN));
  float tt = tanhf(mxn / xn * aa);
  float c = tt / mxn;
  m0 *= c; m1 *= c;
  float xy = blockSum256(m0 * bb0 + m1 * bb1, tmp);
  float y2 = blockSum256(bb0 * bb0 + bb1 * bb1, tmp);
  float x2 = tt * tt;
  float c1 = 1.f + 2.f * xy + y2, c2 = 1.f - x2;
  float iden = 1.f / fmaxf(1.f + 2.f * xy + x2 * y2, 1e-15f);
  float u0 = (c1 * m0 + c2 * bb0) * iden, u1 = (c1 * m1 + c2 * bb1) * iden;
  float un = sqrtf(blockSum256(u0 * u0 + u1 * u1, tmp) + 1e-30f);
  float ps = un > MAXN ? MAXN / un : 1.f;
  float ne = fminf(un, MAXN);
  float f = ps * atanhf(ne) / ne;
  qout[base + t] = f2bf(u0 * f);
  qout[base + t + 256] = f2bf(u1 * f);
}

// ---- attention: per (b,h) MFMA tile. Q,K,V^T bf16 in LDS; S via MFMA;
// register softmax (__shfl_xor over 16-lane key groups); P -> LDS (overlays
// Q/K) in A-layout; PV via MFMA; fp32 out. -------------------------------
__global__ __launch_bounds__(256) void k_attn(const ushort* __restrict__ q,
                                              const ushort* __restrict__ k,
                                              const ushort* __restrict__ v,
                                              float* __restrict__ o) {
  // LDS map (ushorts): Qs[128][72] @0, Ks[128][72] @9216, VTs[64][136] @18432
  // Ps[128][136] @0 (overlays Qs+Ks after QK^T done). Total 54272 B.
  __shared__ __align__(16) ushort smem[27136];
  ushort* Qs = smem;
  ushort* Ks = smem + 9216;
  ushort* VTs = smem + 18432;
  ushort* Ps = smem;
  int bh = blockIdx.x;
  int b = bh >> 3, h = bh & 7;
  int tid = threadIdx.x;
  int w = tid >> 6, lane = tid & 63;
  const size_t BE = (size_t)B_DIM * E_DIM;
  size_t gbase = (size_t)b * E_DIM + (size_t)h * 64;

  // ---- staging: thread t loads half-row (32 bf16) of Q,K,V row s=t>>1 ----
  {
    int s = tid >> 1, half = (tid & 1) * 32;
    const ushort* qr = q + gbase + (size_t)s * BE + half;
    const ushort* kr = k + gbase + (size_t)s * BE + half;
    const ushort* vr = v + gbase + (size_t)s * BE + half;
#pragma unroll
    for (int j = 0; j < 4; ++j) {
      *reinterpret_cast<uint4*>(&Qs[s * 72 + half + j * 8]) =
          *reinterpret_cast<const uint4*>(qr + j * 8);
      *reinterpret_cast<uint4*>(&Ks[s * 72 + half + j * 8]) =
          *reinterpret_cast<const uint4*>(kr + j * 8);
    }
    ushort tv[32];
#pragma unroll
    for (int j = 0; j < 4; ++j)
      *reinterpret_cast<uint4*>(&tv[j * 8]) =
          *reinterpret_cast<const uint4*>(vr + j * 8);
#pragma unroll
    for (int d = 0; d < 32; ++d) VTs[(half + d) * 136 + s] = tv[d];
  }
  __syncthreads();

  // ---- S = QK^T: wave w -> queries [w*32, w*32+32), 2x8 tiles of 16x16 ----
  f32x4 zero = {0.f, 0.f, 0.f, 0.f};
  f32x4 sacc[2][8];
#pragma unroll
  for (int i = 0; i < 2; ++i)
#pragma unroll
    for (int j = 0; j < 8; ++j) sacc[i][j] = zero;
  {
    const ushort* qb = Qs + (w * 32 + (lane & 15)) * 72 + (lane >> 4) * 8;
    const ushort* kb = Ks + (lane & 15) * 72 + (lane >> 4) * 8;
#pragma unroll
    for (int kk = 0; kk < 2; ++kk) {
      bf16x8 a0 = *reinterpret_cast<const bf16x8*>(qb + kk * 32);
      bf16x8 a1 = *reinterpret_cast<const bf16x8*>(qb + 16 * 72 + kk * 32);
#pragma unroll
      for (int tj = 0; tj < 8; ++tj) {
        bf16x8 bf = *reinterpret_cast<const bf16x8*>(kb + tj * 16 * 72 + kk * 32);
        sacc[0][tj] = __builtin_amdgcn_mfma_f32_16x16x32_bf16(a0, bf,
                                                              sacc[0][tj], 0, 0, 0);
        sacc[1][tj] = __builtin_amdgcn_mfma_f32_16x16x32_bf16(a1, bf,
                                                              sacc[1][tj], 0, 0, 0);
      }
    }
  }

  // ---- softmax in registers: keys = lane&15 (x8 tiles); rows = quad*4+reg -
#pragma unroll
  for (int ti = 0; ti < 2; ++ti) {
#pragma unroll
    for (int r = 0; r < 4; ++r) {
      float mx = -1e30f;
#pragma unroll
      for (int tj = 0; tj < 8; ++tj) mx = fmaxf(mx, sacc[ti][tj][r]);
      mx = fmaxf(mx, __shfl_xor(mx, 1));
      mx = fmaxf(mx, __shfl_xor(mx, 2));
      mx = fmaxf(mx, __shfl_xor(mx, 4));
      mx = fmaxf(mx, __shfl_xor(mx, 8));
      float l = 0.f;
#pragma unroll
      for (int tj = 0; tj < 8; ++tj) {
        float e = __expf((sacc[ti][tj][r] - mx) * 0.125f);
        sacc[ti][tj][r] = e;
        l += e;
      }
      l += __shfl_xor(l, 1);
      l += __shfl_xor(l, 2);
      l += __shfl_xor(l, 4);
      l += __shfl_xor(l, 8);
      float inv = 1.f / l;
#pragma unroll
      for (int tj = 0; tj < 8; ++tj) sacc[ti][tj][r] *= inv;
    }
  }

  // ---- P -> LDS in row-major [query][key] (A-operand source), bf16 --------
  __syncthreads();  // all waves done reading Qs/Ks
  {
    int qr0 = w * 32 + (lane >> 4) * 4;
    int kc = lane & 15;
#pragma unroll
    for (int ti = 0; ti < 2; ++ti)
#pragma unroll
      for (int tj = 0; tj < 8; ++tj)
#pragma unroll
        for (int r = 0; r < 4; ++r)
          Ps[(qr0 + ti * 16 + r) * 136 + tj * 16 + kc] =
              f2bf(sacc[ti][tj][r]);
  }
  __syncthreads();

  // ---- O = P V: 2x4 tiles, K-loop over 128 keys ---------------------------
  f32x4 oacc[2][4];
#pragma unroll
  for (int i = 0; i < 2; ++i)
#pragma unroll
    for (int j = 0; j < 4; ++j) oacc[i][j] = zero;
  {
    const ushort* pb = Ps + (w * 32 + (lane & 15)) * 136 + (lane >> 4) * 8;
    const ushort* vb = VTs + (lane & 15) * 136 + (lane >> 4) * 8;
#pragma unroll
    for (int kk = 0; kk < 4; ++kk) {
      bf16x8 a0 = *reinterpret_cast<const bf16x8*>(pb + kk * 32);
      bf16x8 a1 = *reinterpret_cast<const bf16x8*>(pb + 16 * 136 + kk * 32);
#pragma unroll
      for (int tj = 0; tj < 4; ++tj) {
        bf16x8 bv = *reinterpret_cast<const bf16x8*>(vb + tj * 16 * 136 + kk * 32);
        oacc[0][tj] = __builtin_amdgcn_mfma_f32_16x16x32_bf16(a0, bv,
                                                              oacc[0][tj], 0, 0, 0);
        oacc[1][tj] = __builtin_amdgcn_mfma_f32_16x16x32_bf16(a1, bv,
                                                              oacc[1][tj], 0, 0, 0);
      }
    }
  }

  // ---- write O fp32 -------------------------------------------------------
  {
    int qr0 = w * 32 + (lane >> 4) * 4;
    int dc = lane & 15;
#pragma unroll
    for (int ti = 0; ti < 2; ++ti)
#pragma unroll
      for (int tj = 0; tj < 4; ++tj)
#pragma unroll
        for (int r = 0; r < 4; ++r)
          o[(size_t)(qr0 + ti * 16 + r) * BE + gbase + tj * 16 + dc] =
              oacc[ti][tj][r];
  }
}

// ---- expmap0 rowwise (attention out fp32 -> oe bf16), save norm -----------
__global__ __launch_bounds__(256) void k_expmap_rows(const float* __restrict__ in,
                                                     ushort* __restrict__ out,
                                                     float* __restrict__ nrm) {
  __shared__ float tmp[4];
  int row = blockIdx.x, t = threadIdx.x;
  size_t base = (size_t)row * E_DIM;
  float v0 = in[base + t], v1 = in[base + t + 256];
  float n = sqrtf(blockSum256(v0 * v0 + v1 * v1, tmp) + 1e-30f);
  float th = tanhf(n);
  float f = th / n;
  out[base + t] = f2bf(v0 * f);
  out[base + t + 256] = f2bf(v1 * f);
  if (t == 0) nrm[row] = th;
}

// ---- attn-out epilogue: man_linear(Wo) + residual mobius_add + LN2 --------
__global__ __launch_bounds__(256) void k_epi_attnout(
    float* __restrict__ mo, const float* __restrict__ xn_arr,
    const float* __restrict__ bo, const float* __restrict__ xin,
    const float* __restrict__ g2, const float* __restrict__ b2,
    ushort* __restrict__ h2, float* __restrict__ h2n) {
  __shared__ float tmp[4];
  int row = blockIdx.x, t = threadIdx.x;
  size_t base = (size_t)row * E_DIM;
  float m0 = mo[base + t], m1 = mo[base + t + 256];
  float bb0 = bo[t], bb1 = bo[t + 256];
  float mxn = sqrtf(blockSum256(m0 * m0 + m1 * m1, tmp) + 1e-30f);
  float xn = xn_arr[row];
  float aa = atanhf(fminf(xn, MAXN));
  float tt = tanhf(mxn / xn * aa);
  float c = tt / mxn;
  m0 *= c; m1 *= c;
  float xy = blockSum256(m0 * bb0 + m1 * bb1, tmp);
  float y2 = blockSum256(bb0 * bb0 + bb1 * bb1, tmp);
  float x2 = tt * tt;
  float c1 = 1.f + 2.f * xy + y2, c2 = 1.f - x2;
  float iden = 1.f / fmaxf(1.f + 2.f * xy + x2 * y2, 1e-15f);
  float u0 = (c1 * m0 + c2 * bb0) * iden, u1 = (c1 * m1 + c2 * bb1) * iden;
  float un = sqrtf(blockSum256(u0 * u0 + u1 * u1, tmp) + 1e-30f);
  float ps = un > MAXN ? MAXN / un : 1.f;
  float z0 = u0 * ps, z1 = u1 * ps;
  float zn = fminf(un, MAXN);
  float r0 = xin[base + t], r1 = xin[base + t + 256];
  float xy2 = blockSum256(z0 * r0 + z1 * r1, tmp);
  float y22 = blockSum256(r0 * r0 + r1 * r1, tmp);
  float x22 = zn * zn;
  float d1 = 1.f + 2.f * xy2 + y22, d2 = 1.f - x22;
  float iden2 = 1.f / fmaxf(1.f + 2.f * xy2 + x22 * y22, 1e-15f);
  float w0 = (d1 * z0 + d2 * r0) * iden2, w1 = (d1 * z1 + d2 * r1) * iden2;
  float wn = sqrtf(blockSum256(w0 * w0 + w1 * w1, tmp) + 1e-30f);
  float ps2 = wn > MAXN ? MAXN / wn : 1.f;
  w0 *= ps2; w1 *= ps2;
  mo[base + t] = w0;
  mo[base + t + 256] = w1;
  float ne = fminf(wn, MAXN);
  float lf = atanhf(ne) / ne;
  float l0 = w0 * lf, l1 = w1 * lf;
  float mu = blockSum256(l0 + l1, tmp) * (1.f / 512.f);
  float e0 = l0 - mu, e1 = l1 - mu;
  float var = blockSum256(e0 * e0 + e1 * e1, tmp) * (1.f / 512.f);
  float rstd = 1.f / sqrtf(var + 1e-5f);
  e0 = e0 * rstd * g2[t] + b2[t];
  e1 = e1 * rstd * g2[t + 256] + b2[t + 256];
  float n3 = sqrtf(blockSum256(e0 * e0 + e1 * e1, tmp) + 1e-30f);
  float en = tanhf(n3);
  float f = en / n3;
  if (en > MAXN) f *= MAXN / en;
  h2[base + t] = f2bf(e0 * f);
  h2[base + t + 256] = f2bf(e1 * f);
  if (t == 0) h2n[row] = fminf(en, MAXN);
}

// ---- FFN1 epilogue (rows of F): man_linear epi + mob_relu -> bf16 ---------
__global__ __launch_bounds__(256) void k_epi_ffn1(const float* __restrict__ m,
                                                  const float* __restrict__ xn_arr,
                                                  const float* __restrict__ bias,
                                                  ushort* __restrict__ hid,
                                                  float* __restrict__ hn_out) {
  __shared__ float tmp[4];
  int row = blockIdx.x, t = threadIdx.x;
  const float* mr = m + (size_t)row * F_DIM;
  ushort* hr = hid + (size_t)row * F_DIM;
  float mv[8], bvv[8];
  float p = 0.f;
#pragma unroll
  for (int i = 0; i < 8; ++i) {
    mv[i] = mr[t + i * 256];
    bvv[i] = bias[t + i * 256];
    p += mv[i] * mv[i];
  }
  float mxn = sqrtf(blockSum256(p, tmp) + 1e-30f);
  float xn = xn_arr[row];
  float aa = atanhf(fminf(xn, MAXN));
  float tt = tanhf(mxn / xn * aa);
  float c = tt / mxn;
  float pxy = 0.f, py2 = 0.f;
#pragma unroll
  for (int i = 0; i < 8; ++i) {
    mv[i] *= c;
    pxy += mv[i] * bvv[i];
    py2 += bvv[i] * bvv[i];
  }
  float xy = blockSum256(pxy, tmp);
  float y2 = blockSum256(py2, tmp);
  float x2 = tt * tt;
  float c1 = 1.f + 2.f * xy + y2, c2 = 1.f - x2;
  float iden = 1.f / fmaxf(1.f + 2.f * xy + x2 * y2, 1e-15f);
  float pu = 0.f;
#pragma unroll
  for (int i = 0; i < 8; ++i) {
    mv[i] = (c1 * mv[i] + c2 * bvv[i]) * iden;
    pu += mv[i] * mv[i];
  }
  float un = sqrtf(blockSum256(pu, tmp) + 1e-30f);
  float ps = un > MAXN ? MAXN / un : 1.f;
  float zn = fminf(un, MAXN);
  float lf = atanhf(zn) / zn * ps;
  float pr = 0.f;
#pragma unroll
  for (int i = 0; i < 8; ++i) {
    float l = fmaxf(mv[i] * lf, 0.f);
    mv[i] = l;
    pr += l * l;
  }
  float rn = sqrtf(blockSum256(pr, tmp) + 1e-30f);
  float en = tanhf(rn);
  float f = en / rn;
  if (en > MAXN) f *= MAXN / en;
#pragma unroll
  for (int i = 0; i < 8; ++i) hr[t + i * 256] = f2bf(mv[i] * f);
  if (t == 0) hn_out[row] = fminf(en, MAXN);
}

// ---- final epilogue: sum split-K partials + man_linear(W2) + mob_relu +
// residual mobius_add + projx ----------------------------------------------
__global__ __launch_bounds__(256) void k_epi_final(
    const float* __restrict__ m2a, const float* __restrict__ m2b,
    const float* __restrict__ xn_arr, const float* __restrict__ bias,
    const float* __restrict__ res, float* __restrict__ out) {
  __shared__ float tmp[4];
  int row = blockIdx.x, t = threadIdx.x;
  size_t base = (size_t)row * E_DIM;
  float m0 = m2a[base + t] + m2b[base + t];
  float m1 = m2a[base + t + 256] + m2b[base + t + 256];
  float bb0 = bias[t], bb1 = bias[t + 256];
  float mxn = sqrtf(blockSum256(m0 * m0 + m1 * m1, tmp) + 1e-30f);
  float xn = xn_arr[row];
  float aa = atanhf(fminf(xn, MAXN));
  float tt = tanhf(mxn / xn * aa);
  float c = tt / mxn;
  m0 *= c; m1 *= c;
  float xy = blockSum256(m0 * bb0 + m1 * bb1, tmp);
  float y2 = blockSum256(bb0 * bb0 + bb1 * bb1, tmp);
  float x2 = tt * tt;
  float c1 = 1.f + 2.f * xy + y2, c2 = 1.f - x2;
  float iden = 1.f / fmaxf(1.f + 2.f * xy + x2 * y2, 1e-15f);
  float u0 = (c1 * m0 + c2 * bb0) * iden, u1 = (c1 * m1 + c2 * bb1) * iden;
  float un = sqrtf(blockSum256(u0 * u0 + u1 * u1, tmp) + 1e-30f);
  float ps = un > MAXN ? MAXN / un : 1.f;
  float zn = fminf(un, MAXN);
  float lf = atanhf(zn) / zn * ps;
  float r0 = fmaxf(u0 * lf, 0.f), r1 = fmaxf(u1 * lf, 0.f);
  float rn = sqrtf(blockSum256(r0 * r0 + r1 * r1, tmp) + 1e-30f);
  float en = tanhf(rn);
  float f = en / rn;
  if (en > MAXN) f *= MAXN / en;
  float h0 = r0 * f, h1 = r1 * f;
  float hn = fminf(en, MAXN);
  float q0 = res[base + t], q1 = res[base + t + 256];
  float xy2 = blockSum256(h0 * q0 + h1 * q1, tmp);
  float y22 = blockSum256(q0 * q0 + q1 * q1, tmp);
  float x22 = hn * hn;
  float d1 = 1.f + 2.f * xy2 + y22, d2 = 1.f - x22;
  float iden2 = 1.f / fmaxf(1.f + 2.f * xy2 + x22 * y22, 1e-15f);
  float w0 = (d1 * h0 + d2 * q0) * iden2, w1 = (d1 * h1 + d2 * q1) * iden2;
  float wn = sqrtf(blockSum256(w0 * w0 + w1 * w1, tmp) + 1e-30f);
  float ps2 = wn > MAXN ? MAXN / wn : 1.f;
  out[base + t] = w0 * ps2;
  out[base + t + 256] = w1 * ps2;
}

extern "C" void kernel_launch(void* const* d_in, const int* in_sizes, int n_in,
                              void* d_out, int out_size, void* d_ws,
                              size_t ws_size, hipStream_t stream) {
  const float* x   = (const float*)d_in[0];
  const float* g1  = (const float*)d_in[1];
  const float* lb1 = (const float*)d_in[2];
  const float* g2  = (const float*)d_in[3];
  const float* lb2 = (const float*)d_in[4];
  const float* Wq  = (const float*)d_in[5];
  const float* bq  = (const float*)d_in[6];
  const float* Wk  = (const float*)d_in[7];
  const float* bk  = (const float*)d_in[8];
  const float* Wv  = (const float*)d_in[9];
  const float* bv  = (const float*)d_in[10];
  const float* Wo  = (const float*)d_in[11];
  const float* bo  = (const float*)d_in[12];
  const float* W1  = (const float*)d_in[13];
  const float* b1  = (const float*)d_in[14];
  const float* W2  = (const float*)d_in[15];
  const float* b2  = (const float*)d_in[16];
  float* out = (float*)d_out;
  float* ws = (float*)d_ws;

  const size_t NE = (size_t)N_ROWS * E_DIM;          // 16,777,216
  const size_t WF = (4 * (size_t)E_DIM * E_DIM +
                     2 * (size_t)F_DIM * E_DIM) / 2; // 1,572,864 floats
  float* R_b = ws;                   // NE: mx fp32 / attn-out / mo / res2
  float* R_a = ws + NE;              // NE/2: h1_bf16 -> oe_bf16
  float* R_q = ws + NE + NE / 2;     // NE/2: q_bf16 -> h2_bf16
  float* R_k = ws + 2 * NE;          // NE/2: k_bf16 -> m1 fp32 (CH x F)
  float* R_v = ws + 2 * NE + NE / 2; // NE/2: v_bf16 -> hid_bf16 + m2 partials
  ushort* wqb = (ushort*)(ws + 3 * NE);
  ushort* wkb = wqb + (size_t)E_DIM * E_DIM;
  ushort* wvb = wkb + (size_t)E_DIM * E_DIM;
  ushort* wob = wvb + (size_t)E_DIM * E_DIM;
  ushort* w1b = wob + (size_t)E_DIM * E_DIM;
  ushort* w2b = w1b + (size_t)F_DIM * E_DIM;
  float* n_h1 = ws + 3 * NE + WF;
  float* n_oe = n_h1 + N_ROWS;
  float* n_h2 = n_oe + N_ROWS;
  float* n_h3 = n_h2 + N_ROWS;
  const size_t need = (3 * NE + WF + 4 * (size_t)N_ROWS) * sizeof(float);
  if (ws_size < need) return;

  k_f2bf<<<256, 256, 0, stream>>>(Wq, wqb, E_DIM * E_DIM);
  k_f2bf<<<256, 256, 0, stream>>>(Wk, wkb, E_DIM * E_DIM);
  k_f2bf<<<256, 256, 0, stream>>>(Wv, wvb, E_DIM * E_DIM);
  k_f2bf<<<256, 256, 0, stream>>>(Wo, wob, E_DIM * E_DIM);
  k_f2bf<<<512, 256, 0, stream>>>(W1, w1b, F_DIM * E_DIM);
  k_f2bf<<<512, 256, 0, stream>>>(W2, w2b, F_DIM * E_DIM);

  ushort* h1b = (ushort*)R_a;
  ushort* qb = (ushort*)R_q;
  ushort* kb = (ushort*)R_k;
  ushort* vb = (ushort*)R_v;

  // Phase A: stage1 + QKV projections
  k_stage1<<<N_ROWS, 256, 0, stream>>>(x, g1, lb1, h1b, n_h1);
  dim3 gQ(E_DIM / 128, N_ROWS / 128, 1);
  k_gemm_bf16<<<gQ, 256, 0, stream>>>(h1b, wqb, R_b, E_DIM, E_DIM, E_DIM, 0);
  k_epi_qkv<<<N_ROWS, 256, 0, stream>>>(R_b, n_h1, bq, qb);
  k_gemm_bf16<<<gQ, 256, 0, stream>>>(h1b, wkb, R_b, E_DIM, E_DIM, E_DIM, 0);
  k_epi_qkv<<<N_ROWS, 256, 0, stream>>>(R_b, n_h1, bk, kb);
  k_gemm_bf16<<<gQ, 256, 0, stream>>>(h1b, wvb, R_b, E_DIM, E_DIM, E_DIM, 0);
  k_epi_qkv<<<N_ROWS, 256, 0, stream>>>(R_b, n_h1, bv, vb);

  // Phase B: MFMA attention -> R_b fp32; expmap0 -> oe bf16 (R_a, h1 dead)
  k_attn<<<B_DIM * 8, 256, 0, stream>>>(qb, kb, vb, R_b);
  ushort* oeb = (ushort*)R_a;
  k_expmap_rows<<<N_ROWS, 256, 0, stream>>>(R_b, oeb, n_oe);

  // Phase C: Wo projection -> R_b; epilogue: res2 in-place, h2 bf16 -> R_q
  ushort* h2b = (ushort*)R_q;
  k_gemm_bf16<<<gQ, 256, 0, stream>>>(oeb, wob, R_b, E_DIM, E_DIM, E_DIM, 0);
  k_epi_attnout<<<N_ROWS, 256, 0, stream>>>(R_b, n_oe, bo, x, g2, lb2, h2b,
                                            n_h2);

  // Phase D: FFN chunked (CH rows).
  float* m1 = R_k;
  ushort* hidb = (ushort*)R_v;
  float* m2p = R_v + NE / 4;
  const unsigned long long pstr = (unsigned long long)CH * E_DIM;
  for (int c = 0; c < N_ROWS / CH; ++c) {
    size_t ro = (size_t)c * CH;
    k_gemm_bf16<<<dim3(F_DIM / 128, CH / 128, 1), 256, 0, stream>>>(
        h2b + ro * E_DIM, w1b, m1, E_DIM, F_DIM, E_DIM, 0);
    k_epi_ffn1<<<CH, 256, 0, stream>>>(m1, n_h2 + ro, b1, hidb, n_h3 + ro);
    k_gemm_bf16<<<dim3(E_DIM / 128, CH / 128, 2), 256, 0, stream>>>(
        hidb, w2b, m2p, F_DIM, E_DIM, F_DIM / 2, pstr);
    k_epi_final<<<CH, 256, 0, stream>>>(m2p, m2p + pstr, n_h3 + ro, b2,
                                        R_b + ro * E_DIM, out + ro * E_DIM);
  }
}

// Round 5
// 1082.609 us; speedup vs baseline: 3.9376x; 1.4466x over previous
//
// Hyperbolic (Poincare ball) transformer block — MI355X round 5.
// Round-4 + epilogue overhaul: all row-wise kernels are one-WAVE-per-row
// (64 lanes x 8 elems @ E=512, x32 @ F=2048), batched butterfly reductions
// (__shfl_xor), and analytic norms for linear combinations:
//   ||c1*m + c2*b||^2 = c1^2*Sm2 + 2*c1*c2*Smb + c2^2*Sb2  (one pass, not two)
// -> qkv-epi: 1 reduction pass (was 4), attnout: 3 (was 8), zero barriers.
// GEMM (m97 structure) and MFMA flash attention unchanged from round 4.
#include <hip/hip_runtime.h>
#include <math.h>

#define S_DIM 128
#define B_DIM 256
#define E_DIM 512
#define F_DIM 2048
#define N_ROWS (S_DIM * B_DIM) /* 32768 */
#define CH 4096                /* FFN row chunk */
#define MAXN 0.99999f          /* 1 - 1e-5 */

typedef __bf16 bf16x8 __attribute__((ext_vector_type(8)));
typedef float f32x4 __attribute__((ext_vector_type(4)));

__device__ __forceinline__ ushort f2bf(float f) {
  uint u = __float_as_uint(f);
  u += 0x7FFFu + ((u >> 16) & 1u);  // RNE
  return (ushort)(u >> 16);
}
__device__ __forceinline__ uint pack2(float a, float b) {
  return (uint)f2bf(a) | ((uint)f2bf(b) << 16);
}

__device__ __forceinline__ void gld16(const ushort* g, ushort* l) {
  __builtin_amdgcn_global_load_lds(
      (const __attribute__((address_space(1))) void*)g,
      (__attribute__((address_space(3))) void*)l, 16, 0, 0);
}

// ---- wave-wide butterfly reduction of K values (all lanes get results) ----
template <int K>
__device__ __forceinline__ void waveRed(float (&v)[K]) {
#pragma unroll
  for (int o = 1; o < 64; o <<= 1) {
#pragma unroll
    for (int i = 0; i < K; ++i) v[i] += __shfl_xor(v[i], o);
  }
}

// ---------------- fp32 -> bf16 convert (weights) ---------------------------
__global__ __launch_bounds__(256) void k_f2bf(const float* __restrict__ in,
                                              ushort* __restrict__ out, int n) {
  for (int i = blockIdx.x * 256 + threadIdx.x; i < n; i += gridDim.x * 256)
    out[i] = f2bf(in[i]);
}

// ---- stage 1: h1 = expmap0(LN(logmap0(x))) -> bf16, |h1| fp32. Wave/row. --
__global__ __launch_bounds__(256) void k_stage1(const float* __restrict__ x,
                                                const float* __restrict__ g,
                                                const float* __restrict__ bb,
                                                ushort* __restrict__ h,
                                                float* __restrict__ hn) {
  int row = blockIdx.x * 4 + (threadIdx.x >> 6);
  int lane = threadIdx.x & 63;
  size_t base = (size_t)row * E_DIM + lane * 8;
  float v[8], gv[8], bv[8];
  *(float4*)&v[0] = *(const float4*)(x + base);
  *(float4*)&v[4] = *(const float4*)(x + base + 4);
  *(float4*)&gv[0] = *(const float4*)(g + lane * 8);
  *(float4*)&gv[4] = *(const float4*)(g + lane * 8 + 4);
  *(float4*)&bv[0] = *(const float4*)(bb + lane * 8);
  *(float4*)&bv[4] = *(const float4*)(bb + lane * 8 + 4);
  float s[2] = {0.f, 0.f};
#pragma unroll
  for (int i = 0; i < 8; ++i) { s[0] += v[i] * v[i]; s[1] += v[i]; }
  waveRed<2>(s);
  float n = sqrtf(s[0] + 1e-30f);
  float a = atanhf(fminf(n, MAXN)) / n;
  float mu = a * s[1] * (1.f / 512.f);
  float var = fmaxf(a * a * s[0] * (1.f / 512.f) - mu * mu, 0.f);
  float rstd = 1.f / sqrtf(var + 1e-5f);
  float e[8];
  float s2[1] = {0.f};
#pragma unroll
  for (int i = 0; i < 8; ++i) {
    e[i] = (a * v[i] - mu) * rstd * gv[i] + bv[i];
    s2[0] += e[i] * e[i];
  }
  waveRed<1>(s2);
  float n2 = sqrtf(s2[0] + 1e-30f);
  float f = tanhf(n2) / n2;
  uint4 o = {pack2(e[0] * f, e[1] * f), pack2(e[2] * f, e[3] * f),
             pack2(e[4] * f, e[5] * f), pack2(e[6] * f, e[7] * f)};
  *reinterpret_cast<uint4*>(h + base) = o;
  if (lane == 0) hn[row] = tanhf(n2);
}

// -------- bf16 MFMA GEMM: C[n][m] = sum_k A[n][k]*B[m][k], C fp32 ----------
__global__ __launch_bounds__(256) void k_gemm_bf16(
    const ushort* __restrict__ A, const ushort* __restrict__ B,
    float* __restrict__ C, int K, int M, int kseg,
    unsigned long long partStride) {
  __shared__ __align__(16) ushort As[128 * 32];
  __shared__ __align__(16) ushort Bs[128 * 32];
  int tid = threadIdx.x;
  int w = tid >> 6, lane = tid & 63;
  int wm = w >> 1, wn = w & 1;
  size_t row0 = (size_t)blockIdx.y * 128;
  size_t col0 = (size_t)blockIdx.x * 128;
  int k0 = blockIdx.z * kseg;

  const ushort* gA =
      A + (row0 + w * 32 + (lane >> 2)) * (size_t)K + (lane & 3) * 8 + k0;
  const ushort* gB =
      B + (col0 + w * 32 + (lane >> 2)) * (size_t)K + (lane & 3) * 8 + k0;
  ushort* lA = As + (w * 32) * 32;
  ushort* lB = Bs + (w * 32) * 32;
  const int rowK16 = 16 * K;

  int fro = (lane & 15) * 32 + (lane >> 4) * 8;
  const ushort* raA = As + (wm * 64) * 32 + fro;
  const ushort* raB = Bs + (wn * 64) * 32 + fro;

  f32x4 zero = {0.f, 0.f, 0.f, 0.f};
  f32x4 acc[4][4];
#pragma unroll
  for (int i = 0; i < 4; ++i)
#pragma unroll
    for (int j = 0; j < 4; ++j) acc[i][j] = zero;

  for (int kt = 0; kt < kseg; kt += 32) {
    __syncthreads();
    gld16(gA + kt, lA);
    gld16(gA + kt + rowK16, lA + 16 * 32);
    gld16(gB + kt, lB);
    gld16(gB + kt + rowK16, lB + 16 * 32);
    __syncthreads();
    bf16x8 af[4], bfv[4];
#pragma unroll
    for (int t = 0; t < 4; ++t) {
      af[t] = *reinterpret_cast<const bf16x8*>(raA + t * 512);
      bfv[t] = *reinterpret_cast<const bf16x8*>(raB + t * 512);
    }
#pragma unroll
    for (int i = 0; i < 4; ++i)
#pragma unroll
      for (int j = 0; j < 4; ++j)
        acc[i][j] = __builtin_amdgcn_mfma_f32_16x16x32_bf16(af[i], bfv[j],
                                                            acc[i][j], 0, 0, 0);
  }
  float* Cz = C + (size_t)blockIdx.z * partStride;
  int crow = wm * 64 + (lane >> 4) * 4;
  int ccol = (int)col0 + wn * 64 + (lane & 15);
#pragma unroll
  for (int ti = 0; ti < 4; ++ti) {
    size_t r = row0 + crow + ti * 16;
#pragma unroll
    for (int tj = 0; tj < 4; ++tj) {
      int cc = ccol + tj * 16;
#pragma unroll
      for (int reg = 0; reg < 4; ++reg)
        Cz[(r + reg) * (size_t)M + cc] = acc[ti][tj][reg];
    }
  }
}

// ---- QKV epilogue (wave/row, 1 pass): logmap0(projx(mobius_add(mv,b))) ----
__global__ __launch_bounds__(256) void k_epi_qkv(const float* __restrict__ mx,
                                                 const float* __restrict__ xn_arr,
                                                 const float* __restrict__ bias,
                                                 ushort* __restrict__ qout) {
  int row = blockIdx.x * 4 + (threadIdx.x >> 6);
  int lane = threadIdx.x & 63;
  size_t base = (size_t)row * E_DIM + lane * 8;
  float m[8], bv[8];
  *(float4*)&m[0] = *(const float4*)(mx + base);
  *(float4*)&m[4] = *(const float4*)(mx + base + 4);
  *(float4*)&bv[0] = *(const float4*)(bias + lane * 8);
  *(float4*)&bv[4] = *(const float4*)(bias + lane * 8 + 4);
  float s[3] = {0.f, 0.f, 0.f};
#pragma unroll
  for (int i = 0; i < 8; ++i) {
    s[0] += m[i] * m[i]; s[1] += m[i] * bv[i]; s[2] += bv[i] * bv[i];
  }
  waveRed<3>(s);
  float mxn = sqrtf(s[0] + 1e-30f);
  float xn = xn_arr[row];
  float aa = atanhf(fminf(xn, MAXN));
  float tt = tanhf(mxn / xn * aa);
  float c = tt / mxn;
  float xy = c * s[1], y2 = s[2], x2 = tt * tt;
  float c1 = 1.f + 2.f * xy + y2, c2 = 1.f - x2;
  float iden = 1.f / fmaxf(1.f + 2.f * xy + x2 * y2, 1e-15f);
  float cc1 = c1 * c * iden, cc2 = c2 * iden;
  float un2 = fmaxf(cc1 * cc1 * s[0] + 2.f * cc1 * cc2 * s[1] + cc2 * cc2 * s[2], 0.f);
  float un = sqrtf(un2 + 1e-30f);
  float ps = un > MAXN ? MAXN / un : 1.f;
  float ne = fminf(un, MAXN);
  float f = ps * atanhf(ne) / ne;
  float u[8];
#pragma unroll
  for (int i = 0; i < 8; ++i) u[i] = (cc1 * m[i] + cc2 * bv[i]) * f;
  uint4 o = {pack2(u[0], u[1]), pack2(u[2], u[3]), pack2(u[4], u[5]),
             pack2(u[6], u[7])};
  *reinterpret_cast<uint4*>(qout + base) = o;
}

// ---- attention: per (b,h) MFMA tile (unchanged from round 4) --------------
__global__ __launch_bounds__(256) void k_attn(const ushort* __restrict__ q,
                                              const ushort* __restrict__ k,
                                              const ushort* __restrict__ v,
                                              float* __restrict__ o) {
  __shared__ __align__(16) ushort smem[27136];
  ushort* Qs = smem;
  ushort* Ks = smem + 9216;
  ushort* VTs = smem + 18432;
  ushort* Ps = smem;
  int bh = blockIdx.x;
  int b = bh >> 3, h = bh & 7;
  int tid = threadIdx.x;
  int w = tid >> 6, lane = tid & 63;
  const size_t BE = (size_t)B_DIM * E_DIM;
  size_t gbase = (size_t)b * E_DIM + (size_t)h * 64;

  {
    int s = tid >> 1, half = (tid & 1) * 32;
    const ushort* qr = q + gbase + (size_t)s * BE + half;
    const ushort* kr = k + gbase + (size_t)s * BE + half;
    const ushort* vr = v + gbase + (size_t)s * BE + half;
#pragma unroll
    for (int j = 0; j < 4; ++j) {
      *reinterpret_cast<uint4*>(&Qs[s * 72 + half + j * 8]) =
          *reinterpret_cast<const uint4*>(qr + j * 8);
      *reinterpret_cast<uint4*>(&Ks[s * 72 + half + j * 8]) =
          *reinterpret_cast<const uint4*>(kr + j * 8);
    }
    ushort tv[32];
#pragma unroll
    for (int j = 0; j < 4; ++j)
      *reinterpret_cast<uint4*>(&tv[j * 8]) =
          *reinterpret_cast<const uint4*>(vr + j * 8);
#pragma unroll
    for (int d = 0; d < 32; ++d) VTs[(half + d) * 136 + s] = tv[d];
  }
  __syncthreads();

  f32x4 zero = {0.f, 0.f, 0.f, 0.f};
  f32x4 sacc[2][8];
#pragma unroll
  for (int i = 0; i < 2; ++i)
#pragma unroll
    for (int j = 0; j < 8; ++j) sacc[i][j] = zero;
  {
    const ushort* qb = Qs + (w * 32 + (lane & 15)) * 72 + (lane >> 4) * 8;
    const ushort* kb = Ks + (lane & 15) * 72 + (lane >> 4) * 8;
#pragma unroll
    for (int kk = 0; kk < 2; ++kk) {
      bf16x8 a0 = *reinterpret_cast<const bf16x8*>(qb + kk * 32);
      bf16x8 a1 = *reinterpret_cast<const bf16x8*>(qb + 16 * 72 + kk * 32);
#pragma unroll
      for (int tj = 0; tj < 8; ++tj) {
        bf16x8 bf = *reinterpret_cast<const bf16x8*>(kb + tj * 16 * 72 + kk * 32);
        sacc[0][tj] = __builtin_amdgcn_mfma_f32_16x16x32_bf16(a0, bf,
                                                              sacc[0][tj], 0, 0, 0);
        sacc[1][tj] = __builtin_amdgcn_mfma_f32_16x16x32_bf16(a1, bf,
                                                              sacc[1][tj], 0, 0, 0);
      }
    }
  }

#pragma unroll
  for (int ti = 0; ti < 2; ++ti) {
#pragma unroll
    for (int r = 0; r < 4; ++r) {
      float mx = -1e30f;
#pragma unroll
      for (int tj = 0; tj < 8; ++tj) mx = fmaxf(mx, sacc[ti][tj][r]);
      mx = fmaxf(mx, __shfl_xor(mx, 1));
      mx = fmaxf(mx, __shfl_xor(mx, 2));
      mx = fmaxf(mx, __shfl_xor(mx, 4));
      mx = fmaxf(mx, __shfl_xor(mx, 8));
      float l = 0.f;
#pragma unroll
      for (int tj = 0; tj < 8; ++tj) {
        float e = __expf((sacc[ti][tj][r] - mx) * 0.125f);
        sacc[ti][tj][r] = e;
        l += e;
      }
      l += __shfl_xor(l, 1);
      l += __shfl_xor(l, 2);
      l += __shfl_xor(l, 4);
      l += __shfl_xor(l, 8);
      float inv = 1.f / l;
#pragma unroll
      for (int tj = 0; tj < 8; ++tj) sacc[ti][tj][r] *= inv;
    }
  }

  __syncthreads();
  {
    int qr0 = w * 32 + (lane >> 4) * 4;
    int kc = lane & 15;
#pragma unroll
    for (int ti = 0; ti < 2; ++ti)
#pragma unroll
      for (int tj = 0; tj < 8; ++tj)
#pragma unroll
        for (int r = 0; r < 4; ++r)
          Ps[(qr0 + ti * 16 + r) * 136 + tj * 16 + kc] =
              f2bf(sacc[ti][tj][r]);
  }
  __syncthreads();

  f32x4 oacc[2][4];
#pragma unroll
  for (int i = 0; i < 2; ++i)
#pragma unroll
    for (int j = 0; j < 4; ++j) oacc[i][j] = zero;
  {
    const ushort* pb = Ps + (w * 32 + (lane & 15)) * 136 + (lane >> 4) * 8;
    const ushort* vb = VTs + (lane & 15) * 136 + (lane >> 4) * 8;
#pragma unroll
    for (int kk = 0; kk < 4; ++kk) {
      bf16x8 a0 = *reinterpret_cast<const bf16x8*>(pb + kk * 32);
      bf16x8 a1 = *reinterpret_cast<const bf16x8*>(pb + 16 * 136 + kk * 32);
#pragma unroll
      for (int tj = 0; tj < 4; ++tj) {
        bf16x8 bv = *reinterpret_cast<const bf16x8*>(vb + tj * 16 * 136 + kk * 32);
        oacc[0][tj] = __builtin_amdgcn_mfma_f32_16x16x32_bf16(a0, bv,
                                                              oacc[0][tj], 0, 0, 0);
        oacc[1][tj] = __builtin_amdgcn_mfma_f32_16x16x32_bf16(a1, bv,
                                                              oacc[1][tj], 0, 0, 0);
      }
    }
  }

  {
    int qr0 = w * 32 + (lane >> 4) * 4;
    int dc = lane & 15;
#pragma unroll
    for (int ti = 0; ti < 2; ++ti)
#pragma unroll
      for (int tj = 0; tj < 4; ++tj)
#pragma unroll
        for (int r = 0; r < 4; ++r)
          o[(size_t)(qr0 + ti * 16 + r) * BE + gbase + tj * 16 + dc] =
              oacc[ti][tj][r];
  }
}

// ---- expmap0 rowwise (wave/row, 1 pass) -----------------------------------
__global__ __launch_bounds__(256) void k_expmap_rows(const float* __restrict__ in,
                                                     ushort* __restrict__ out,
                                                     float* __restrict__ nrm) {
  int row = blockIdx.x * 4 + (threadIdx.x >> 6);
  int lane = threadIdx.x & 63;
  size_t base = (size_t)row * E_DIM + lane * 8;
  float v[8];
  *(float4*)&v[0] = *(const float4*)(in + base);
  *(float4*)&v[4] = *(const float4*)(in + base + 4);
  float s[1] = {0.f};
#pragma unroll
  for (int i = 0; i < 8; ++i) s[0] += v[i] * v[i];
  waveRed<1>(s);
  float n = sqrtf(s[0] + 1e-30f);
  float th = tanhf(n);
  float f = th / n;
  uint4 o = {pack2(v[0] * f, v[1] * f), pack2(v[2] * f, v[3] * f),
             pack2(v[4] * f, v[5] * f), pack2(v[6] * f, v[7] * f)};
  *reinterpret_cast<uint4*>(out + base) = o;
  if (lane == 0) nrm[row] = th;
}

// ---- attn-out epilogue (wave/row, 3 passes): man_linear(Wo) + residual
// mobius_add + projx (res2 fp32 in-place) + LN2 chain -> h2 bf16 ------------
__global__ __launch_bounds__(256) void k_epi_attnout(
    float* __restrict__ mo, const float* __restrict__ xn_arr,
    const float* __restrict__ bo, const float* __restrict__ xin,
    const float* __restrict__ g2, const float* __restrict__ b2,
    ushort* __restrict__ h2, float* __restrict__ h2n) {
  int row = blockIdx.x * 4 + (threadIdx.x >> 6);
  int lane = threadIdx.x & 63;
  size_t base = (size_t)row * E_DIM + lane * 8;
  float m[8], bv[8];
  *(float4*)&m[0] = *(const float4*)(mo + base);
  *(float4*)&m[4] = *(const float4*)(mo + base + 4);
  *(float4*)&bv[0] = *(const float4*)(bo + lane * 8);
  *(float4*)&bv[4] = *(const float4*)(bo + lane * 8 + 4);
  float s[5] = {0.f, 0.f, 0.f, 0.f, 0.f};
#pragma unroll
  for (int i = 0; i < 8; ++i) {
    s[0] += m[i] * m[i]; s[1] += m[i] * bv[i]; s[2] += bv[i] * bv[i];
    s[3] += m[i]; s[4] += bv[i];
  }
  waveRed<5>(s);
  float mxn = sqrtf(s[0] + 1e-30f);
  float xn = xn_arr[row];
  float aa = atanhf(fminf(xn, MAXN));
  float tt = tanhf(mxn / xn * aa);
  float c = tt / mxn;
  float xy = c * s[1], y2 = s[2], x2 = tt * tt;
  float c1 = 1.f + 2.f * xy + y2, c2 = 1.f - x2;
  float iden = 1.f / fmaxf(1.f + 2.f * xy + x2 * y2, 1e-15f);
  float cc1 = c1 * c * iden, cc2 = c2 * iden;
  float un2 = fmaxf(cc1 * cc1 * s[0] + 2.f * cc1 * cc2 * s[1] + cc2 * cc2 * s[2], 0.f);
  float un = sqrtf(un2 + 1e-30f);
  float ps = un > MAXN ? MAXN / un : 1.f;
  float zn = fminf(un, MAXN);
  float z[8];
#pragma unroll
  for (int i = 0; i < 8; ++i) z[i] = (cc1 * m[i] + cc2 * bv[i]) * ps;
  float sumz = ps * (cc1 * s[3] + cc2 * s[4]);
  // mobius_add(z, xin) + projx
  float r[8];
  *(float4*)&r[0] = *(const float4*)(xin + base);
  *(float4*)&r[4] = *(const float4*)(xin + base + 4);
  float t2[3] = {0.f, 0.f, 0.f};
#pragma unroll
  for (int i = 0; i < 8; ++i) {
    t2[0] += z[i] * r[i]; t2[1] += r[i] * r[i]; t2[2] += r[i];
  }
  waveRed<3>(t2);
  float xy2 = t2[0], y22 = t2[1], x22 = zn * zn;
  float d1 = 1.f + 2.f * xy2 + y22, d2 = 1.f - x22;
  float iden2 = 1.f / fmaxf(1.f + 2.f * xy2 + x22 * y22, 1e-15f);
  float wn2 = fmaxf(iden2 * iden2 *
                        (d1 * d1 * x22 + 2.f * d1 * d2 * xy2 + d2 * d2 * y22),
                    0.f);
  float wn = sqrtf(wn2 + 1e-30f);
  float ps2 = wn > MAXN ? MAXN / wn : 1.f;
  float w[8];
#pragma unroll
  for (int i = 0; i < 8; ++i) w[i] = (d1 * z[i] + d2 * r[i]) * iden2 * ps2;
  *(float4*)(mo + base) = *(float4*)&w[0];
  *(float4*)(mo + base + 4) = *(float4*)&w[4];
  // logmap0 -> LN2 -> expmap0 -> projx
  float ne = fminf(wn, MAXN);
  float lf = atanhf(ne) / ne;
  float sumw = ps2 * iden2 * (d1 * sumz + d2 * t2[2]);
  float mu = lf * sumw * (1.f / 512.f);
  float sl2 = lf * ne;  // sqrt(Sum l^2) = atanh(ne)... lf*ne = atanh(ne)
  float var = fmaxf(sl2 * sl2 * (1.f / 512.f) - mu * mu, 0.f);
  float rstd = 1.f / sqrtf(var + 1e-5f);
  float gv[8], b2v[8];
  *(float4*)&gv[0] = *(const float4*)(g2 + lane * 8);
  *(float4*)&gv[4] = *(const float4*)(g2 + lane * 8 + 4);
  *(float4*)&b2v[0] = *(const float4*)(b2 + lane * 8);
  *(float4*)&b2v[4] = *(const float4*)(b2 + lane * 8 + 4);
  float e[8];
  float s3[1] = {0.f};
#pragma unroll
  for (int i = 0; i < 8; ++i) {
    e[i] = (lf * w[i] - mu) * rstd * gv[i] + b2v[i];
    s3[0] += e[i] * e[i];
  }
  waveRed<1>(s3);
  float n3 = sqrtf(s3[0] + 1e-30f);
  float en = tanhf(n3);
  float f = en / n3;
  if (en > MAXN) f *= MAXN / en;
  uint4 o = {pack2(e[0] * f, e[1] * f), pack2(e[2] * f, e[3] * f),
             pack2(e[4] * f, e[5] * f), pack2(e[6] * f, e[7] * f)};
  *reinterpret_cast<uint4*>(h2 + base) = o;
  if (lane == 0) h2n[row] = fminf(en, MAXN);
}

// ---- FFN1 epilogue (wave/row of F=2048, 2 passes) -> bf16 -----------------
__global__ __launch_bounds__(256) void k_epi_ffn1(const float* __restrict__ mr_,
                                                  const float* __restrict__ xn_arr,
                                                  const float* __restrict__ bias,
                                                  ushort* __restrict__ hid,
                                                  float* __restrict__ hn_out) {
  int row = blockIdx.x * 4 + (threadIdx.x >> 6);
  int lane = threadIdx.x & 63;
  const float* mr = mr_ + (size_t)row * F_DIM + lane * 32;
  const float* br = bias + lane * 32;
  float m[32], bv[32];
#pragma unroll
  for (int j = 0; j < 8; ++j) {
    *(float4*)&m[j * 4] = *(const float4*)(mr + j * 4);
    *(float4*)&bv[j * 4] = *(const float4*)(br + j * 4);
  }
  float s[3] = {0.f, 0.f, 0.f};
#pragma unroll
  for (int i = 0; i < 32; ++i) {
    s[0] += m[i] * m[i]; s[1] += m[i] * bv[i]; s[2] += bv[i] * bv[i];
  }
  waveRed<3>(s);
  float mxn = sqrtf(s[0] + 1e-30f);
  float xn = xn_arr[row];
  float aa = atanhf(fminf(xn, MAXN));
  float tt = tanhf(mxn / xn * aa);
  float c = tt / mxn;
  float xy = c * s[1], y2 = s[2], x2 = tt * tt;
  float c1 = 1.f + 2.f * xy + y2, c2 = 1.f - x2;
  float iden = 1.f / fmaxf(1.f + 2.f * xy + x2 * y2, 1e-15f);
  float cc1 = c1 * c * iden, cc2 = c2 * iden;
  float un2 = fmaxf(cc1 * cc1 * s[0] + 2.f * cc1 * cc2 * s[1] + cc2 * cc2 * s[2], 0.f);
  float un = sqrtf(un2 + 1e-30f);
  float ps = un > MAXN ? MAXN / un : 1.f;
  float zn = fminf(un, MAXN);
  float lf = atanhf(zn) / zn * ps;
  float s2[1] = {0.f};
#pragma unroll
  for (int i = 0; i < 32; ++i) {
    m[i] = fmaxf((cc1 * m[i] + cc2 * bv[i]) * lf, 0.f);
    s2[0] += m[i] * m[i];
  }
  waveRed<1>(s2);
  float rn = sqrtf(s2[0] + 1e-30f);
  float en = tanhf(rn);
  float f = en / rn;
  if (en > MAXN) f *= MAXN / en;
  ushort* hr = hid + (size_t)row * F_DIM + lane * 32;
#pragma unroll
  for (int j = 0; j < 4; ++j) {
    uint4 o = {pack2(m[j * 8 + 0] * f, m[j * 8 + 1] * f),
               pack2(m[j * 8 + 2] * f, m[j * 8 + 3] * f),
               pack2(m[j * 8 + 4] * f, m[j * 8 + 5] * f),
               pack2(m[j * 8 + 6] * f, m[j * 8 + 7] * f)};
    *reinterpret_cast<uint4*>(hr + j * 8) = o;
  }
  if (lane == 0) hn_out[row] = fminf(en, MAXN);
}

// ---- final epilogue (wave/row, 2 passes): split-K sum + man_linear(W2) +
// mob_relu + residual mobius_add + projx -> out fp32 ------------------------
__global__ __launch_bounds__(256) void k_epi_final(
    const float* __restrict__ m2a, const float* __restrict__ m2b,
    const float* __restrict__ xn_arr, const float* __restrict__ bias,
    const float* __restrict__ res, float* __restrict__ out) {
  int row = blockIdx.x * 4 + (threadIdx.x >> 6);
  int lane = threadIdx.x & 63;
  size_t base = (size_t)row * E_DIM + lane * 8;
  float m[8], bv[8], ta[8], tb[8];
  *(float4*)&ta[0] = *(const float4*)(m2a + base);
  *(float4*)&ta[4] = *(const float4*)(m2a + base + 4);
  *(float4*)&tb[0] = *(const float4*)(m2b + base);
  *(float4*)&tb[4] = *(const float4*)(m2b + base + 4);
  *(float4*)&bv[0] = *(const float4*)(bias + lane * 8);
  *(float4*)&bv[4] = *(const float4*)(bias + lane * 8 + 4);
  float s[3] = {0.f, 0.f, 0.f};
#pragma unroll
  for (int i = 0; i < 8; ++i) {
    m[i] = ta[i] + tb[i];
    s[0] += m[i] * m[i]; s[1] += m[i] * bv[i]; s[2] += bv[i] * bv[i];
  }
  waveRed<3>(s);
  float mxn = sqrtf(s[0] + 1e-30f);
  float xn = xn_arr[row];
  float aa = atanhf(fminf(xn, MAXN));
  float tt = tanhf(mxn / xn * aa);
  float c = tt / mxn;
  float xy = c * s[1], y2 = s[2], x2 = tt * tt;
  float c1 = 1.f + 2.f * xy + y2, c2 = 1.f - x2;
  float iden = 1.f / fmaxf(1.f + 2.f * xy + x2 * y2, 1e-15f);
  float cc1 = c1 * c * iden, cc2 = c2 * iden;
  float un2 = fmaxf(cc1 * cc1 * s[0] + 2.f * cc1 * cc2 * s[1] + cc2 * cc2 * s[2], 0.f);
  float un = sqrtf(un2 + 1e-30f);
  float ps = un > MAXN ? MAXN / un : 1.f;
  float zn = fminf(un, MAXN);
  float lf = atanhf(zn) / zn * ps;
  float r[8], q[8];
  *(float4*)&q[0] = *(const float4*)(res + base);
  *(float4*)&q[4] = *(const float4*)(res + base + 4);
  float s2[3] = {0.f, 0.f, 0.f};
#pragma unroll
  for (int i = 0; i < 8; ++i) {
    r[i] = fmaxf((cc1 * m[i] + cc2 * bv[i]) * lf, 0.f);
    s2[0] += r[i] * r[i]; s2[1] += r[i] * q[i]; s2[2] += q[i] * q[i];
  }
  waveRed<3>(s2);
  float rn = sqrtf(s2[0] + 1e-30f);
  float en = tanhf(rn);
  float f = en / rn;
  if (en > MAXN) f *= MAXN / en;
  float hn = fminf(en, MAXN);
  float xy2 = f * s2[1], y22 = s2[2], x22 = hn * hn;
  float d1 = 1.f + 2.f * xy2 + y22, d2 = 1.f - x22;
  float iden2 = 1.f / fmaxf(1.f + 2.f * xy2 + x22 * y22, 1e-15f);
  float wn2 = fmaxf(iden2 * iden2 *
                        (d1 * d1 * x22 + 2.f * d1 * d2 * xy2 + d2 * d2 * y22),
                    0.f);
  float wn = sqrtf(wn2 + 1e-30f);
  float ps2 = wn > MAXN ? MAXN / wn : 1.f;
  float w[8];
#pragma unroll
  for (int i = 0; i < 8; ++i)
    w[i] = (d1 * r[i] * f + d2 * q[i]) * iden2 * ps2;
  *(float4*)(out + base) = *(float4*)&w[0];
  *(float4*)(out + base + 4) = *(float4*)&w[4];
}

extern "C" void kernel_launch(void* const* d_in, const int* in_sizes, int n_in,
                              void* d_out, int out_size, void* d_ws,
                              size_t ws_size, hipStream_t stream) {
  const float* x   = (const float*)d_in[0];
  const float* g1  = (const float*)d_in[1];
  const float* lb1 = (const float*)d_in[2];
  const float* g2  = (const float*)d_in[3];
  const float* lb2 = (const float*)d_in[4];
  const float* Wq  = (const float*)d_in[5];
  const float* bq  = (const float*)d_in[6];
  const float* Wk  = (const float*)d_in[7];
  const float* bk  = (const float*)d_in[8];
  const float* Wv  = (const float*)d_in[9];
  const float* bv  = (const float*)d_in[10];
  const float* Wo  = (const float*)d_in[11];
  const float* bo  = (const float*)d_in[12];
  const float* W1  = (const float*)d_in[13];
  const float* b1  = (const float*)d_in[14];
  const float* W2  = (const float*)d_in[15];
  const float* b2  = (const float*)d_in[16];
  float* out = (float*)d_out;
  float* ws = (float*)d_ws;

  const size_t NE = (size_t)N_ROWS * E_DIM;          // 16,777,216
  const size_t WF = (4 * (size_t)E_DIM * E_DIM +
                     2 * (size_t)F_DIM * E_DIM) / 2; // 1,572,864 floats
  float* R_b = ws;                   // NE: mx fp32 / attn-out / mo / res2
  float* R_a = ws + NE;              // NE/2: h1_bf16 -> oe_bf16
  float* R_q = ws + NE + NE / 2;     // NE/2: q_bf16 -> h2_bf16
  float* R_k = ws + 2 * NE;          // NE/2: k_bf16 -> m1 fp32 (CH x F)
  float* R_v = ws + 2 * NE + NE / 2; // NE/2: v_bf16 -> hid_bf16 + m2 partials
  ushort* wqb = (ushort*)(ws + 3 * NE);
  ushort* wkb = wqb + (size_t)E_DIM * E_DIM;
  ushort* wvb = wkb + (size_t)E_DIM * E_DIM;
  ushort* wob = wvb + (size_t)E_DIM * E_DIM;
  ushort* w1b = wob + (size_t)E_DIM * E_DIM;
  ushort* w2b = w1b + (size_t)F_DIM * E_DIM;
  float* n_h1 = ws + 3 * NE + WF;
  float* n_oe = n_h1 + N_ROWS;
  float* n_h2 = n_oe + N_ROWS;
  float* n_h3 = n_h2 + N_ROWS;
  const size_t need = (3 * NE + WF + 4 * (size_t)N_ROWS) * sizeof(float);
  if (ws_size < need) return;

  k_f2bf<<<256, 256, 0, stream>>>(Wq, wqb, E_DIM * E_DIM);
  k_f2bf<<<256, 256, 0, stream>>>(Wk, wkb, E_DIM * E_DIM);
  k_f2bf<<<256, 256, 0, stream>>>(Wv, wvb, E_DIM * E_DIM);
  k_f2bf<<<256, 256, 0, stream>>>(Wo, wob, E_DIM * E_DIM);
  k_f2bf<<<512, 256, 0, stream>>>(W1, w1b, F_DIM * E_DIM);
  k_f2bf<<<512, 256, 0, stream>>>(W2, w2b, F_DIM * E_DIM);

  ushort* h1b = (ushort*)R_a;
  ushort* qb = (ushort*)R_q;
  ushort* kb = (ushort*)R_k;
  ushort* vb = (ushort*)R_v;

  // Phase A: stage1 + QKV projections
  k_stage1<<<N_ROWS / 4, 256, 0, stream>>>(x, g1, lb1, h1b, n_h1);
  dim3 gQ(E_DIM / 128, N_ROWS / 128, 1);
  k_gemm_bf16<<<gQ, 256, 0, stream>>>(h1b, wqb, R_b, E_DIM, E_DIM, E_DIM, 0);
  k_epi_qkv<<<N_ROWS / 4, 256, 0, stream>>>(R_b, n_h1, bq, qb);
  k_gemm_bf16<<<gQ, 256, 0, stream>>>(h1b, wkb, R_b, E_DIM, E_DIM, E_DIM, 0);
  k_epi_qkv<<<N_ROWS / 4, 256, 0, stream>>>(R_b, n_h1, bk, kb);
  k_gemm_bf16<<<gQ, 256, 0, stream>>>(h1b, wvb, R_b, E_DIM, E_DIM, E_DIM, 0);
  k_epi_qkv<<<N_ROWS / 4, 256, 0, stream>>>(R_b, n_h1, bv, vb);

  // Phase B: MFMA attention -> R_b fp32; expmap0 -> oe bf16 (R_a, h1 dead)
  k_attn<<<B_DIM * 8, 256, 0, stream>>>(qb, kb, vb, R_b);
  ushort* oeb = (ushort*)R_a;
  k_expmap_rows<<<N_ROWS / 4, 256, 0, stream>>>(R_b, oeb, n_oe);

  // Phase C: Wo projection -> R_b; epilogue: res2 in-place, h2 bf16 -> R_q
  ushort* h2b = (ushort*)R_q;
  k_gemm_bf16<<<gQ, 256, 0, stream>>>(oeb, wob, R_b, E_DIM, E_DIM, E_DIM, 0);
  k_epi_attnout<<<N_ROWS / 4, 256, 0, stream>>>(R_b, n_oe, bo, x, g2, lb2,
                                                h2b, n_h2);

  // Phase D: FFN chunked (CH rows).
  float* m1 = R_k;
  ushort* hidb = (ushort*)R_v;
  float* m2p = R_v + NE / 4;
  const unsigned long long pstr = (unsigned long long)CH * E_DIM;
  for (int c = 0; c < N_ROWS / CH; ++c) {
    size_t ro = (size_t)c * CH;
    k_gemm_bf16<<<dim3(F_DIM / 128, CH / 128, 1), 256, 0, stream>>>(
        h2b + ro * E_DIM, w1b, m1, E_DIM, F_DIM, E_DIM, 0);
    k_epi_ffn1<<<CH / 4, 256, 0, stream>>>(m1, n_h2 + ro, b1, hidb, n_h3 + ro);
    k_gemm_bf16<<<dim3(E_DIM / 128, CH / 128, 2), 256, 0, stream>>>(
        hidb, w2b, m2p, F_DIM, E_DIM, F_DIM / 2, pstr);
    k_epi_final<<<CH / 4, 256, 0, stream>>>(m2p, m2p + pstr, n_h3 + ro, b2,
                                            R_b + ro * E_DIM, out + ro * E_DIM);
  }
}